// Round 6
// baseline (2908.704 us; speedup 1.0000x reference)
//
#include <hip/hip_runtime.h>
#include <hip/hip_bf16.h>
#include <float.h>
#include <math.h>

// Problem constants
#define NB 4
#define ND 512
#define NS 512
#define NH 8
#define NHD 64
#define NM 8192
#define NL 6
#define NFF 2048
#define NMLP 1024
#define NC 117

// knn4 params
#define KCC 128               // m's per chunk
#define NCC (NM / KCC)        // 64 chunks
#define CAPB 224              // buffer capacity per query
#define TRIG 96               // shrink trigger: TRIG + KCC == CAPB -> no overflow

typedef __attribute__((ext_vector_type(8))) short s16x8;
typedef __attribute__((ext_vector_type(4))) float f32x4;

__device__ __forceinline__ float gelu_f(float x) {
    return 0.5f * x * (1.0f + erff(x * 0.70710678118654752440f));
}

__device__ __forceinline__ ushort f2bf_rne(float x) {
    uint u = __float_as_uint(x);
    uint r = u + 0x7FFFu + ((u >> 16) & 1u);
    return (ushort)(r >> 16);
}
__device__ __forceinline__ float bf2f(ushort h) { return __uint_as_float(((uint)h) << 16); }
__device__ __forceinline__ void split1(float x, ushort& h, ushort& l) {
    h = f2bf_rne(x);
    float r = x - bf2f(h);
    l = f2bf_rne(r);
}
__device__ __forceinline__ void split8(const float* v, s16x8& hv, s16x8& lv) {
#pragma unroll
    for (int j = 0; j < 8; ++j) {
        ushort h, l;
        split1(v[j], h, l);
        hv[j] = (short)h;
        lv[j] = (short)l;
    }
}

// sortable key: (value desc, index asc) -> larger key wins; valid keys are nonzero
__device__ __forceinline__ unsigned long long packkey(float v, int idx) {
    uint u = __float_as_uint(v);
    u = u ^ (((int)u < 0) ? 0xFFFFFFFFu : 0x80000000u);
    return (((unsigned long long)u) << 13) | (unsigned long long)(8191 - idx);
}

// wave-parallel exact top-32 of cval/cidx[q][0..n) -> slots 0..31 sorted desc.
// STATIC register indexing only (rule #20: no runtime-indexed locals -> no scratch).
__device__ __forceinline__ void shrink32(float* __restrict__ cval,
                                         ushort* __restrict__ cidx,
                                         int q, int n, int lane,
                                         float* __restrict__ thrOut) {
    float v0, v1, v2, v3;
    int i0, i1, i2, i3;
    unsigned long long k0, k1, k2, k3;
    {
        int j0 = lane, j1 = lane + 64, j2 = lane + 128, j3 = lane + 192;
        bool o0 = j0 < n, o1 = j1 < n, o2 = j2 < n, o3 = j3 < n;
        v0 = o0 ? cval[q * CAPB + j0] : 0.f; i0 = o0 ? (int)cidx[q * CAPB + j0] : 0;
        v1 = o1 ? cval[q * CAPB + j1] : 0.f; i1 = o1 ? (int)cidx[q * CAPB + j1] : 0;
        v2 = o2 ? cval[q * CAPB + j2] : 0.f; i2 = o2 ? (int)cidx[q * CAPB + j2] : 0;
        v3 = o3 ? cval[q * CAPB + j3] : 0.f; i3 = o3 ? (int)cidx[q * CAPB + j3] : 0;
        k0 = o0 ? packkey(v0, i0) : 0ULL;
        k1 = o1 ? packkey(v1, i1) : 0ULL;
        k2 = o2 ? packkey(v2, i2) : 0ULL;
        k3 = o3 ? packkey(v3, i3) : 0ULL;
    }
    unsigned long long kb = k0;
    float vb = v0;
    int ib = i0;
    if (k1 > kb) { kb = k1; vb = v1; ib = i1; }
    if (k2 > kb) { kb = k2; vb = v2; ib = i2; }
    if (k3 > kb) { kb = k3; vb = v3; ib = i3; }
    for (int r = 0; r < 32; ++r) {
        unsigned long long m = kb;
#pragma unroll
        for (int off = 32; off; off >>= 1) {
            unsigned long long o = __shfl_xor(m, off);
            if (o > m) m = o;
        }
        if (kb == m) {  // unique winner lane (keys are unique)
            cval[q * CAPB + r] = vb;
            cidx[q * CAPB + r] = (ushort)ib;
            if (thrOut && r == 31) *thrOut = vb;
            k0 = (k0 == kb) ? 0ULL : k0;
            k1 = (k1 == kb) ? 0ULL : k1;
            k2 = (k2 == kb) ? 0ULL : k2;
            k3 = (k3 == kb) ? 0ULL : k3;
            kb = k0; vb = v0; ib = i0;
            if (k1 > kb) { kb = k1; vb = v1; ib = i1; }
            if (k2 > kb) { kb = k2; vb = v2; ib = i2; }
            if (k3 > kb) { kb = k3; vb = v3; ib = i3; }
        }
    }
}

// ---- mask 64^3 -> 8^3 trilinear (degenerates to 2x2x2 box avg at offsets 3,4) ----
__global__ void k_m8(const float* __restrict__ mask, float* __restrict__ m8) {
    int b = blockIdx.x, sp = threadIdx.x;
    int a = sp >> 6, bb = (sp >> 3) & 7, cc = sp & 7;
    const float* mb = mask + (size_t)b * 262144;
    int i0 = 8 * a + 3, j0 = 8 * bb + 3, k0 = 8 * cc + 3;
    float s = 0.f;
#pragma unroll
    for (int di = 0; di < 2; ++di)
#pragma unroll
        for (int dj = 0; dj < 2; ++dj)
#pragma unroll
            for (int dk = 0; dk < 2; ++dk)
                s += mb[(i0 + di) * 4096 + (j0 + dj) * 64 + (k0 + dk)];
    m8[b * NS + sp] = s * 0.125f;
}

// ---- tok[b][s][d] = x[b][d][s]*m8[b][s] + pe[d][s]  (tiled transpose) ----
__global__ void k_tok(const float* __restrict__ x, const float* __restrict__ pe,
                      const float* __restrict__ m8, float* __restrict__ tok) {
    __shared__ float t[32][33];
    int b = blockIdx.z;
    int sp0 = blockIdx.x * 32, d0 = blockIdx.y * 32;
    int tx = threadIdx.x, ty = threadIdx.y;
#pragma unroll
    for (int i = 0; i < 4; ++i) {
        int d = d0 + ty + i * 8;
        int sp = sp0 + tx;
        float v = x[((size_t)(b * ND + d)) * NS + sp] * m8[b * NS + sp] + pe[(size_t)d * NS + sp];
        t[ty + i * 8][tx] = v;
    }
    __syncthreads();
#pragma unroll
    for (int i = 0; i < 4; ++i) {
        int sp = sp0 + ty + i * 8;
        int d = d0 + tx;
        tok[((size_t)(b * NS) + sp) * ND + d] = t[tx][ty + i * 8];
    }
}

// ---- mem_k fp32 -> bf16 hi/lo (same [b][m][d] layout) ----
__global__ void k_mksplit(const float* __restrict__ mk, ushort* __restrict__ mh,
                          ushort* __restrict__ ml) {
    size_t i4 = ((size_t)blockIdx.x * 256 + threadIdx.x) * 4;
    float4 v = *(const float4*)&mk[i4];
    float vv[4] = {v.x, v.y, v.z, v.w};
    ushort h[4], l[4];
#pragma unroll
    for (int j = 0; j < 4; ++j) split1(vv[j], h[j], l[j]);
    *(ushort4*)&mh[i4] = make_ushort4(h[0], h[1], h[2], h[3]);
    *(ushort4*)&ml[i4] = make_ushort4(l[0], l[1], l[2], l[3]);
}

// ---- split-bf16 MFMA GEMM: C = epi(A @ W + bias [+resid]), 3-pass hi/lo ----
template <int BM, int BN, int EPI>
__global__ __launch_bounds__(256) void k_gmm(
    const float* __restrict__ A, const float* __restrict__ W,
    const float* __restrict__ bias, const float* __restrict__ resid,
    float* __restrict__ C, int M, int N, int K) {
    constexpr int PAD = 40;
    constexpr int FM = BM / 32, FN = BN / 32;
    __shared__ __align__(16) ushort Ah[BM * PAD];
    __shared__ __align__(16) ushort Al[BM * PAD];
    __shared__ __align__(16) ushort Bh[BN * PAD];
    __shared__ __align__(16) ushort Bl[BN * PAD];
    int tid = threadIdx.x, lane = tid & 63, wvi = tid >> 6;
    int wr = wvi >> 1, wc = wvi & 1;
    int bn = blockIdx.x * BN, bm = blockIdx.y * BM;

    constexpr int FPTA = BM / 8;
    constexpr int TPRA = 32 / FPTA;
    int arow = tid / TPRA;
    int akoff = (tid % TPRA) * FPTA;
    const float* Ap = A + (size_t)(bm + arow) * K + akoff;

    constexpr int FPTB = BN / 8;
    int bkrow = tid >> 3;
    int bnoff = (tid & 7) * FPTB;
    const float* Wp = W + (size_t)bkrow * N + bn + bnoff;

    float abuf[FPTA], bbuf[FPTB];
#pragma unroll
    for (int j = 0; j < FPTA; j += 4) *(float4*)&abuf[j] = *(const float4*)(Ap + j);
#pragma unroll
    for (int j = 0; j < FPTB; j += 4) *(float4*)&bbuf[j] = *(const float4*)(Wp + j);

    f32x4 acc[FM][FN] = {};

    for (int k0 = 0; k0 < K; k0 += 32) {
#pragma unroll
        for (int g = 0; g < FPTA / 8; ++g) {
            s16x8 hv, lv;
            split8(&abuf[g * 8], hv, lv);
            *(s16x8*)&Ah[arow * PAD + akoff + g * 8] = hv;
            *(s16x8*)&Al[arow * PAD + akoff + g * 8] = lv;
        }
#pragma unroll
        for (int j = 0; j < FPTB; ++j) {
            ushort h, l;
            split1(bbuf[j], h, l);
            Bh[(bnoff + j) * PAD + bkrow] = h;
            Bl[(bnoff + j) * PAD + bkrow] = l;
        }
        __syncthreads();
        if (k0 + 32 < K) {
#pragma unroll
            for (int j = 0; j < FPTA; j += 4)
                *(float4*)&abuf[j] = *(const float4*)(Ap + k0 + 32 + j);
#pragma unroll
            for (int j = 0; j < FPTB; j += 4)
                *(float4*)&bbuf[j] = *(const float4*)(Wp + (size_t)(k0 + 32) * N + j);
        }
        s16x8 fah[FM], fal[FM], fbh[FN], fbl[FN];
        int kb = (lane >> 4) * 8;
#pragma unroll
        for (int fm = 0; fm < FM; ++fm) {
            int row = wr * (BM / 2) + fm * 16 + (lane & 15);
            fah[fm] = *(const s16x8*)&Ah[row * PAD + kb];
            fal[fm] = *(const s16x8*)&Al[row * PAD + kb];
        }
#pragma unroll
        for (int fn = 0; fn < FN; ++fn) {
            int row = wc * (BN / 2) + fn * 16 + (lane & 15);
            fbh[fn] = *(const s16x8*)&Bh[row * PAD + kb];
            fbl[fn] = *(const s16x8*)&Bl[row * PAD + kb];
        }
#pragma unroll
        for (int fm = 0; fm < FM; ++fm)
#pragma unroll
            for (int fn = 0; fn < FN; ++fn) {
                acc[fm][fn] = __builtin_amdgcn_mfma_f32_16x16x32_bf16(fah[fm], fbh[fn], acc[fm][fn], 0, 0, 0);
                acc[fm][fn] = __builtin_amdgcn_mfma_f32_16x16x32_bf16(fah[fm], fbl[fn], acc[fm][fn], 0, 0, 0);
                acc[fm][fn] = __builtin_amdgcn_mfma_f32_16x16x32_bf16(fal[fm], fbh[fn], acc[fm][fn], 0, 0, 0);
            }
        __syncthreads();
    }
#pragma unroll
    for (int fm = 0; fm < FM; ++fm) {
#pragma unroll
        for (int fn = 0; fn < FN; ++fn) {
            int n = bn + wc * (BN / 2) + fn * 16 + (lane & 15);
            float bb = bias[n];
#pragma unroll
            for (int r = 0; r < 4; ++r) {
                int m = bm + wr * (BM / 2) + fm * 16 + (lane >> 4) * 4 + r;
                float o = acc[fm][fn][r] + bb;
                if (EPI == 1) o = gelu_f(o);
                else if (EPI == 2) o += resid[(size_t)m * N + n];
                C[(size_t)m * N + n] = o;
            }
        }
    }
}

// ---- fused flash attention: per (b,h,32-row q tile) ----
__global__ __launch_bounds__(256) void k_attn(const float* __restrict__ qkv,
                                              float* __restrict__ ao) {
    __shared__ float qs[32][65];
    __shared__ float ks[64][65];
    __shared__ float sc[32][68];
    __shared__ float pm[32][8];
    __shared__ float Mrow[32], Srow[32], Arow[32];
    int s0 = blockIdx.x * 32, h = blockIdx.y, b = blockIdx.z;
    int tid = threadIdx.x, tx = tid & 15, ty = tid >> 4;
    const float* base = qkv + (size_t)b * NS * 1536;
#pragma unroll
    for (int i = 0; i < 8; ++i) {
        int idx = tid + i * 256;
        int r = idx >> 6, d = idx & 63;
        qs[r][d] = base[(size_t)(s0 + r) * 1536 + h * 64 + d] * 0.125f;
    }
    if (tid < 32) { Mrow[tid] = -FLT_MAX; Srow[tid] = 0.f; }
    float accp[2][4] = {};
    int rg = tid >> 3, gg = tid & 7;
    for (int c = 0; c < 8; ++c) {
        __syncthreads();
#pragma unroll
        for (int i = 0; i < 16; ++i) {
            int idx = tid + i * 256;
            int r = idx >> 6, d = idx & 63;
            ks[r][d] = base[(size_t)(c * 64 + r) * 1536 + 512 + h * 64 + d];
        }
        __syncthreads();
        float a00 = 0, a01 = 0, a02 = 0, a03 = 0, a10 = 0, a11 = 0, a12 = 0, a13 = 0;
#pragma unroll 8
        for (int d = 0; d < 64; ++d) {
            float q0 = qs[ty][d], q1 = qs[ty + 16][d];
            float k0 = ks[tx][d], k1 = ks[tx + 16][d], k2 = ks[tx + 32][d], k3 = ks[tx + 48][d];
            a00 += q0 * k0; a01 += q0 * k1; a02 += q0 * k2; a03 += q0 * k3;
            a10 += q1 * k0; a11 += q1 * k1; a12 += q1 * k2; a13 += q1 * k3;
        }
        sc[ty][tx] = a00; sc[ty][tx + 16] = a01; sc[ty][tx + 32] = a02; sc[ty][tx + 48] = a03;
        sc[ty + 16][tx] = a10; sc[ty + 16][tx + 16] = a11; sc[ty + 16][tx + 32] = a12; sc[ty + 16][tx + 48] = a13;
        __syncthreads();
        float lm = -FLT_MAX;
#pragma unroll
        for (int j = 0; j < 8; ++j) lm = fmaxf(lm, sc[rg][gg * 8 + j]);
        pm[rg][gg] = lm;
        __syncthreads();
        if (gg == 0) {
            float nm = Mrow[rg];
#pragma unroll
            for (int j = 0; j < 8; ++j) nm = fmaxf(nm, pm[rg][j]);
            Arow[rg] = __expf(Mrow[rg] - nm);
            Mrow[rg] = nm;
        }
        __syncthreads();
        float mr = Mrow[rg];
        float ssp = 0.f;
#pragma unroll
        for (int j = 0; j < 8; ++j) {
            float e = __expf(sc[rg][gg * 8 + j] - mr);
            sc[rg][gg * 8 + j] = e;
            ssp += e;
        }
        pm[rg][gg] = ssp;
        __syncthreads();
        if (gg == 0) {
            float s2 = 0.f;
#pragma unroll
            for (int j = 0; j < 8; ++j) s2 += pm[rg][j];
            Srow[rg] = Srow[rg] * Arow[rg] + s2;
        }
        float al0 = Arow[ty], al1 = Arow[ty + 16];
#pragma unroll
        for (int j = 0; j < 4; ++j) { accp[0][j] *= al0; accp[1][j] *= al1; }
        __syncthreads();
#pragma unroll
        for (int i = 0; i < 16; ++i) {
            int idx = tid + i * 256;
            int r = idx >> 6, d = idx & 63;
            ks[r][d] = base[(size_t)(c * 64 + r) * 1536 + 1024 + h * 64 + d];
        }
        __syncthreads();
#pragma unroll 8
        for (int kk = 0; kk < 64; ++kk) {
            float p0 = sc[ty][kk], p1 = sc[ty + 16][kk];
            float v0 = ks[kk][tx], v1 = ks[kk][tx + 16], v2 = ks[kk][tx + 32], v3 = ks[kk][tx + 48];
            accp[0][0] += p0 * v0; accp[0][1] += p0 * v1; accp[0][2] += p0 * v2; accp[0][3] += p0 * v3;
            accp[1][0] += p1 * v0; accp[1][1] += p1 * v1; accp[1][2] += p1 * v2; accp[1][3] += p1 * v3;
        }
    }
    __syncthreads();
    float inv0 = 1.0f / Srow[ty], inv1 = 1.0f / Srow[ty + 16];
    size_t o0 = ((size_t)(b * NS) + s0 + ty) * ND + h * 64;
    size_t o1 = ((size_t)(b * NS) + s0 + ty + 16) * ND + h * 64;
    ao[o0 + tx] = accp[0][0] * inv0;
    ao[o0 + tx + 16] = accp[0][1] * inv0;
    ao[o0 + tx + 32] = accp[0][2] * inv0;
    ao[o0 + tx + 48] = accp[0][3] * inv0;
    ao[o1 + tx] = accp[1][0] * inv1;
    ao[o1 + tx + 16] = accp[1][1] * inv1;
    ao[o1 + tx + 32] = accp[1][2] * inv1;
    ao[o1 + tx + 48] = accp[1][3] * inv1;
}

// ==== KNN v4b: threshold-append buffers + rare wave-parallel shrink (static regs) ====
// grid (NS/4, NB): block = (b, 4 s) -> 32 queries (8h x 4s), 256 threads.
__global__ __launch_bounds__(256) void k_knn4(
    const float* __restrict__ qkv, const ushort* __restrict__ mkh,
    const ushort* __restrict__ mkl, const float* __restrict__ mv,
    const float* __restrict__ gate, float* __restrict__ ao) {
    __shared__ __align__(16) char SM[76288];
    ushort* kh = (ushort*)SM;
    ushort* kl = (ushort*)(SM + 16384);
    float* cval = (float*)(SM + 32768);
    ushort* cidx = (ushort*)(SM + 61440);
    float* thrV = (float*)(SM + 75776);
    int* cnt = (int*)(SM + 75904);
    int* sflag = (int*)(SM + 76032);
    ushort* qh = (ushort*)(SM + 32768);  // prologue overlay (4KB)
    ushort* ql = (ushort*)(SM + 36864);  // prologue overlay (4KB)

    int b = blockIdx.y, s0 = blockIdx.x * 4;
    int tid = threadIdx.x, lane = tid & 63, wvi = tid >> 6;
    size_t mbase = (size_t)b * NM;

    // ---- prologue: stage q (scaled, split, swizzled) ----
    {
        int q = tid >> 3, dbase = (tid & 7) * 8;
        const float* src = &qkv[((size_t)(b * NS) + s0 + (q & 3)) * 1536 + (q >> 2) * 64 + dbase];
        float v[8];
#pragma unroll
        for (int j = 0; j < 8; ++j) v[j] = src[j] * 0.125f;
        s16x8 hv, lv;
        split8(v, hv, lv);
        int by = q * 128 + ((dbase * 2) ^ ((q & 7) << 4));
        *(s16x8*)((char*)qh + by) = hv;
        *(s16x8*)((char*)ql + by) = lv;
    }
    // issue chunk-0 loads: thread t<128 -> kh row t; t>=128 -> kl row t-128
    int srow = tid & 127;
    const ushort* sbase0 = (tid < 128 ? mkh : mkl);
    uint4 sg[8];
    {
        const ushort* p = sbase0 + (mbase + srow) * 64;
#pragma unroll
        for (int i = 0; i < 8; ++i) sg[i] = *(const uint4*)(p + i * 8);
    }
    __syncthreads();  // q staged
    // hoist q fragments (chunk-invariant)
    s16x8 fqh[2][2], fql[2][2];  // [fq][kstep]
#pragma unroll
    for (int fq = 0; fq < 2; ++fq)
#pragma unroll
        for (int ks = 0; ks < 2; ++ks) {
            int row = fq * 16 + (lane & 15);
            int kb2 = (ks * 32 + (lane >> 4) * 8) * 2;
            int by = row * 128 + (kb2 ^ ((row & 7) << 4));
            fqh[fq][ks] = *(const s16x8*)((const char*)qh + by);
            fql[fq][ks] = *(const s16x8*)((const char*)ql + by);
        }
    if (tid < 32) { cnt[tid] = 0; thrV[tid] = -FLT_MAX; }
    if (tid == 0) *sflag = 0;
    // write chunk 0 (kh/kl disjoint from qh/ql overlay)
    {
        ushort* dst = (tid < 128 ? kh : kl);
        int byb = srow * 128, sw = (srow & 7) << 4;
#pragma unroll
        for (int i = 0; i < 8; ++i)
            *(uint4*)((char*)dst + byb + ((i * 16) ^ sw)) = sg[i];
    }

    int qbase4 = (lane >> 4) * 4;  // C-frag row group

    for (int c = 0; c < NCC; ++c) {
        __syncthreads();  // A: k[c] ready; cnt/thr/flag consistent
        // threshold cache for this thread's 8 queries
        float thc[2][4];
#pragma unroll
        for (int fq = 0; fq < 2; ++fq)
#pragma unroll
            for (int r = 0; r < 4; ++r) thc[fq][r] = thrV[fq * 16 + qbase4 + r];

        // ---- sims: 3-pass split-bf16 MFMA; wave owns 32 m's (2 frags) ----
        f32x4 acc[2][2] = {};  // [fq][fm]
#pragma unroll
        for (int ks = 0; ks < 2; ++ks) {
            int kb2 = (ks * 32 + (lane >> 4) * 8) * 2;
#pragma unroll
            for (int fm = 0; fm < 2; ++fm) {
                int row = wvi * 32 + fm * 16 + (lane & 15);
                int by = row * 128 + (kb2 ^ ((row & 7) << 4));
                s16x8 kh8 = *(const s16x8*)((const char*)kh + by);
                s16x8 kl8 = *(const s16x8*)((const char*)kl + by);
#pragma unroll
                for (int fq = 0; fq < 2; ++fq) {
                    acc[fq][fm] = __builtin_amdgcn_mfma_f32_16x16x32_bf16(fqh[fq][ks], kh8, acc[fq][fm], 0, 0, 0);
                    acc[fq][fm] = __builtin_amdgcn_mfma_f32_16x16x32_bf16(fqh[fq][ks], kl8, acc[fq][fm], 0, 0, 0);
                    acc[fq][fm] = __builtin_amdgcn_mfma_f32_16x16x32_bf16(fql[fq][ks], kh8, acc[fq][fm], 0, 0, 0);
                }
            }
        }

        // issue next-chunk loads (hide under appends/merge)
        if (c + 1 < NCC) {
            const ushort* p = sbase0 + (mbase + (size_t)(c + 1) * KCC + srow) * 64;
#pragma unroll
            for (int i = 0; i < 8; ++i) sg[i] = *(const uint4*)(p + i * 8);
        }

        // ---- appends: unordered, threshold-gated; eager shrink flag ----
#pragma unroll
        for (int fq = 0; fq < 2; ++fq)
#pragma unroll
            for (int fm = 0; fm < 2; ++fm)
#pragma unroll
                for (int r = 0; r < 4; ++r) {
                    float v = acc[fq][fm][r];
                    if (v >= thc[fq][r]) {
                        int q = fq * 16 + qbase4 + r;
                        int pos = atomicAdd(&cnt[q], 1);
                        if (pos < CAPB) {
                            cval[q * CAPB + pos] = v;
                            cidx[q * CAPB + pos] = (ushort)(c * KCC + wvi * 32 + fm * 16 + (lane & 15));
                        }
                        if (pos == TRIG) *sflag = 1;
                    }
                }
        __syncthreads();  // B: appends done; k reads done

        if (*sflag) {  // block-uniform
#pragma unroll 1
            for (int qq = 0; qq < 8; ++qq) {
                int q = wvi * 8 + qq;
                int n = cnt[q];
                if (n <= TRIG) continue;
                shrink32(cval, cidx, q, n, lane, &thrV[q]);
                if (lane == 0) cnt[q] = 32;
            }
            __syncthreads();  // C: shrink done
            if (tid == 0) *sflag = 0;
        }

        // write staged k for chunk c+1
        if (c + 1 < NCC) {
            ushort* dst = (tid < 128 ? kh : kl);
            int byb = srow * 128, sw = (srow & 7) << 4;
#pragma unroll
            for (int i = 0; i < 8; ++i)
                *(uint4*)((char*)dst + byb + ((i * 16) ^ sw)) = sg[i];
        }
    }

    // ---- final shrink (unconditional, exact top-32 sorted desc) ----
#pragma unroll 1
    for (int qq = 0; qq < 8; ++qq) {
        int q = wvi * 8 + qq;
        shrink32(cval, cidx, q, cnt[q], lane, nullptr);
    }
    __syncthreads();

    // ---- softmax weights (slot 0 = max by construction) ----
    if (tid < 32) {
        int q = tid;
        float mx = cval[q * CAPB];
        float es[32];
        float ssum = 0.f;
#pragma unroll
        for (int j = 0; j < 32; ++j) { es[j] = __expf(cval[q * CAPB + j] - mx); ssum += es[j]; }
        float inv = 1.0f / ssum;
#pragma unroll
        for (int j = 0; j < 32; ++j) cval[q * CAPB + j] = es[j] * inv;
    }
    __syncthreads();

    // ---- gather mem_v and blend into ao: 8 threads/query, 8 d each ----
    {
        int q = tid >> 3, dseg = (tid & 7) * 8;
        int h = q >> 2, si = q & 3;
        float r0x = 0, r0y = 0, r0z = 0, r0w = 0, r1x = 0, r1y = 0, r1z = 0, r1w = 0;
        const float* vb = mv + (size_t)b * NM * NHD;
        for (int j = 0; j < 32; ++j) {
            float w = cval[q * CAPB + j];
            int idx = (int)cidx[q * CAPB + j];
            const float* row = vb + (size_t)idx * NHD + dseg;
            float4 v0 = *(const float4*)(row);
            float4 v1 = *(const float4*)(row + 4);
            r0x += w * v0.x; r0y += w * v0.y; r0z += w * v0.z; r0w += w * v0.w;
            r1x += w * v1.x; r1y += w * v1.y; r1z += w * v1.z; r1w += w * v1.w;
        }
        float g = 1.0f / (1.0f + __expf(-gate[h]));
        float omg = 1.0f - g;
        float* aop = ao + ((size_t)(b * NS) + s0 + si) * ND + h * 64 + dseg;
        float rr[8] = {r0x, r0y, r0z, r0w, r1x, r1y, r1z, r1w};
#pragma unroll
        for (int k = 0; k < 8; ++k) aop[k] = aop[k] * omg + rr[k] * g;
    }
}

// ---- LayerNorm over D=512 per row ----
__global__ __launch_bounds__(256) void k_ln(const float* __restrict__ X,
                                            const float* __restrict__ gam,
                                            const float* __restrict__ bet,
                                            float* __restrict__ Y) {
    __shared__ float red[4];
    __shared__ float sm, sv;
    int r = blockIdx.x, tid = threadIdx.x;
    const float* xr = X + (size_t)r * ND;
    float x0 = xr[tid], x1 = xr[tid + 256];
    float s = x0 + x1;
    for (int off = 32; off; off >>= 1) s += __shfl_down(s, off);
    if ((tid & 63) == 0) red[tid >> 6] = s;
    __syncthreads();
    if (tid == 0) sm = (red[0] + red[1] + red[2] + red[3]) * (1.0f / 512.0f);
    __syncthreads();
    float m = sm;
    float d0 = x0 - m, d1 = x1 - m;
    float vs = d0 * d0 + d1 * d1;
    for (int off = 32; off; off >>= 1) vs += __shfl_down(vs, off);
    if ((tid & 63) == 0) red[tid >> 6] = vs;
    __syncthreads();
    if (tid == 0) sv = rsqrtf((red[0] + red[1] + red[2] + red[3]) * (1.0f / 512.0f) + 1e-5f);
    __syncthreads();
    float rstd = sv;
    Y[(size_t)r * ND + tid] = d0 * rstd * gam[tid] + bet[tid];
    Y[(size_t)r * ND + tid + 256] = d1 * rstd * gam[tid + 256] + bet[tid + 256];
}

// ---- mean pool over S ----
__global__ void k_pool(const float* __restrict__ tok, float* __restrict__ pooled) {
    int b = blockIdx.x, d = threadIdx.x;
    float s = 0.f;
    for (int sp = 0; sp < NS; ++sp) s += tok[((size_t)(b * NS) + sp) * ND + d];
    pooled[b * ND + d] = s * (1.0f / 512.0f);
}

__global__ void k_fc1(const float* __restrict__ pooled, const float* __restrict__ w,
                      const float* __restrict__ bias, float* __restrict__ o1) {
    int id = blockIdx.x * 256 + threadIdx.x;  // 4096
    int b = id >> 10, j = id & 1023;
    float acc = bias[j];
    for (int d = 0; d < ND; ++d) acc += pooled[b * ND + d] * w[(size_t)d * NMLP + j];
    o1[id] = gelu_f(acc);
}

__global__ void k_fc2(const float* __restrict__ o1, const float* __restrict__ w,
                      const float* __restrict__ bias, float* __restrict__ out) {
    int id = blockIdx.x * 256 + threadIdx.x;
    if (id >= NB * NC) return;
    int b = id / NC, c = id % NC;
    float acc = bias[c];
    for (int k = 0; k < NMLP; ++k) acc += o1[b * NMLP + k] * w[(size_t)k * NC + c];
    out[id] = acc;
}

extern "C" void kernel_launch(void* const* d_in, const int* in_sizes, int n_in,
                              void* d_out, int out_size, void* d_ws, size_t ws_size,
                              hipStream_t stream) {
    const float* x    = (const float*)d_in[0];
    const float* mask = (const float*)d_in[1];
    const float* pe   = (const float*)d_in[2];
    const float* Wqkv = (const float*)d_in[3];
    const float* bqkv = (const float*)d_in[4];
    const float* Wo   = (const float*)d_in[5];
    const float* bo   = (const float*)d_in[6];
    const float* ln1g = (const float*)d_in[7];
    const float* ln1b = (const float*)d_in[8];
    const float* W1   = (const float*)d_in[9];
    const float* b1   = (const float*)d_in[10];
    const float* W2   = (const float*)d_in[11];
    const float* b2   = (const float*)d_in[12];
    const float* ln2g = (const float*)d_in[13];
    const float* ln2b = (const float*)d_in[14];
    const float* gate = (const float*)d_in[15];
    const float* memk = (const float*)d_in[16];
    const float* memv = (const float*)d_in[17];
    const float* fc1w = (const float*)d_in[18];
    const float* fc1b = (const float*)d_in[19];
    const float* fc2w = (const float*)d_in[20];
    const float* fc2b = (const float*)d_in[21];
    float* out = (float*)d_out;

    float* ws = (float*)d_ws;
    float* m8     = ws;                       // 2048
    ushort* mkh   = (ushort*)(m8 + 2048);     // 2097152 ushort
    ushort* mkl   = mkh + 2097152;            // 2097152 ushort
    float* tok    = (float*)(mkl + 2097152);  // 1048576
    float* qkv    = tok + 1048576;            // 3145728
    float* ao     = qkv + 3145728;            // 1048576
    float* ybuf   = ao + 1048576;             // 1048576
    float* ff1    = ybuf + 1048576;           // 4194304
    float* pooled = ff1 + 4194304;            // 2048
    float* o1     = pooled + 2048;            // 4096

    k_m8<<<NB, 512, 0, stream>>>(mask, m8);
    k_mksplit<<<2048, 256, 0, stream>>>(memk, mkh, mkl);
    k_tok<<<dim3(16, 16, NB), dim3(32, 8), 0, stream>>>(x, pe, m8, tok);

    for (int l = 0; l < NL; ++l) {
        k_gmm<128, 128, 0><<<dim3(12, 16), 256, 0, stream>>>(
            tok, Wqkv + (size_t)l * 512 * 1536, bqkv + l * 1536, nullptr, qkv, 2048, 1536, 512);
        k_attn<<<dim3(16, NH, NB), 256, 0, stream>>>(qkv, ao);
        if (l == 0)
            k_knn4<<<dim3(NS / 4, NB), 256, 0, stream>>>(qkv, mkh, mkl, memv, gate, ao);
        k_gmm<64, 64, 2><<<dim3(8, 32), 256, 0, stream>>>(
            ao, Wo + (size_t)l * 512 * 512, bo + l * 512, tok, ybuf, 2048, 512, 512);
        k_ln<<<2048, 256, 0, stream>>>(ybuf, ln1g + l * 512, ln1b + l * 512, tok);
        k_gmm<128, 128, 1><<<dim3(16, 16), 256, 0, stream>>>(
            tok, W1 + (size_t)l * 512 * 2048, b1 + l * 2048, nullptr, ff1, 2048, 2048, 512);
        k_gmm<64, 64, 2><<<dim3(8, 32), 256, 0, stream>>>(
            ff1, W2 + (size_t)l * 2048 * 512, b2 + l * 512, tok, ybuf, 2048, 512, 2048);
        k_ln<<<2048, 256, 0, stream>>>(ybuf, ln2g + l * 512, ln2b + l * 512, tok);
    }

    k_pool<<<NB, 512, 0, stream>>>(tok, pooled);
    k_fc1<<<16, 256, 0, stream>>>(pooled, fc1w, fc1b, o1);
    k_fc2<<<2, 256, 0, stream>>>(o1, fc2w, fc2b, out);
}

// Round 7
// 2746.352 us; speedup vs baseline: 1.0591x; 1.0591x over previous
//
#include <hip/hip_runtime.h>
#include <hip/hip_bf16.h>
#include <float.h>
#include <math.h>

// Problem constants
#define NB 4
#define ND 512
#define NS 512
#define NH 8
#define NHD 64
#define NM 8192
#define NL 6
#define NFF 2048
#define NMLP 1024
#define NC 117

// knn4 params
#define KCC 128               // m's per chunk
#define NCC (NM / KCC)        // 64 chunks
#define CAPB 224              // buffer capacity per query
#define TRIG 96               // shrink trigger: TRIG + KCC == CAPB -> no overflow

#define AS1 __attribute__((address_space(1)))
#define AS3 __attribute__((address_space(3)))

typedef __attribute__((ext_vector_type(8))) short s16x8;
typedef __attribute__((ext_vector_type(4))) float f32x4;

__device__ __forceinline__ float gelu_f(float x) {
    return 0.5f * x * (1.0f + erff(x * 0.70710678118654752440f));
}

__device__ __forceinline__ ushort f2bf_rne(float x) {
    uint u = __float_as_uint(x);
    uint r = u + 0x7FFFu + ((u >> 16) & 1u);
    return (ushort)(r >> 16);
}
__device__ __forceinline__ float bf2f(ushort h) { return __uint_as_float(((uint)h) << 16); }
__device__ __forceinline__ void split1(float x, ushort& h, ushort& l) {
    h = f2bf_rne(x);
    float r = x - bf2f(h);
    l = f2bf_rne(r);
}
__device__ __forceinline__ void split8(const float* v, s16x8& hv, s16x8& lv) {
#pragma unroll
    for (int j = 0; j < 8; ++j) {
        ushort h, l;
        split1(v[j], h, l);
        hv[j] = (short)h;
        lv[j] = (short)l;
    }
}

// sortable key: (value desc, index asc) -> larger key wins; valid keys are nonzero
__device__ __forceinline__ unsigned long long packkey(float v, int idx) {
    uint u = __float_as_uint(v);
    u = u ^ (((int)u < 0) ? 0xFFFFFFFFu : 0x80000000u);
    return (((unsigned long long)u) << 13) | (unsigned long long)(8191 - idx);
}

// wave-parallel exact top-32 of cval/cidx[q][0..n) -> slots 0..31 sorted desc.
// STATIC register indexing only (rule #20).
__device__ __forceinline__ void shrink32(float* __restrict__ cval,
                                         ushort* __restrict__ cidx,
                                         int q, int n, int lane,
                                         float* __restrict__ thrOut) {
    float v0, v1, v2, v3;
    int i0, i1, i2, i3;
    unsigned long long k0, k1, k2, k3;
    {
        int j0 = lane, j1 = lane + 64, j2 = lane + 128, j3 = lane + 192;
        bool o0 = j0 < n, o1 = j1 < n, o2 = j2 < n, o3 = j3 < n;
        v0 = o0 ? cval[q * CAPB + j0] : 0.f; i0 = o0 ? (int)cidx[q * CAPB + j0] : 0;
        v1 = o1 ? cval[q * CAPB + j1] : 0.f; i1 = o1 ? (int)cidx[q * CAPB + j1] : 0;
        v2 = o2 ? cval[q * CAPB + j2] : 0.f; i2 = o2 ? (int)cidx[q * CAPB + j2] : 0;
        v3 = o3 ? cval[q * CAPB + j3] : 0.f; i3 = o3 ? (int)cidx[q * CAPB + j3] : 0;
        k0 = o0 ? packkey(v0, i0) : 0ULL;
        k1 = o1 ? packkey(v1, i1) : 0ULL;
        k2 = o2 ? packkey(v2, i2) : 0ULL;
        k3 = o3 ? packkey(v3, i3) : 0ULL;
    }
    unsigned long long kb = k0;
    float vb = v0;
    int ib = i0;
    if (k1 > kb) { kb = k1; vb = v1; ib = i1; }
    if (k2 > kb) { kb = k2; vb = v2; ib = i2; }
    if (k3 > kb) { kb = k3; vb = v3; ib = i3; }
    for (int r = 0; r < 32; ++r) {
        unsigned long long m = kb;
#pragma unroll
        for (int off = 32; off; off >>= 1) {
            unsigned long long o = __shfl_xor(m, off);
            if (o > m) m = o;
        }
        if (kb == m) {  // unique winner lane (keys are unique)
            cval[q * CAPB + r] = vb;
            cidx[q * CAPB + r] = (ushort)ib;
            if (thrOut && r == 31) *thrOut = vb;
            k0 = (k0 == kb) ? 0ULL : k0;
            k1 = (k1 == kb) ? 0ULL : k1;
            k2 = (k2 == kb) ? 0ULL : k2;
            k3 = (k3 == kb) ? 0ULL : k3;
            kb = k0; vb = v0; ib = i0;
            if (k1 > kb) { kb = k1; vb = v1; ib = i1; }
            if (k2 > kb) { kb = k2; vb = v2; ib = i2; }
            if (k3 > kb) { kb = k3; vb = v3; ib = i3; }
        }
    }
}

// async DMA of one 16KB-per-buffer chunk (128 rows x 128B) into kh/kl.
// Sources are PRE-SWIZZLED, so dest is linear (rule #21). Drained by next barrier.
__device__ __forceinline__ void stage_dma(const ushort* __restrict__ gh,
                                          const ushort* __restrict__ gl,
                                          ushort* kh, ushort* kl,
                                          int wvi, int lane) {
#pragma unroll
    for (int i = 0; i < 4; ++i) {
        int off = (wvi * 4 + i) * 1024;  // bytes
        __builtin_amdgcn_global_load_lds(
            (const AS1 uint*)((const char*)gh + off + lane * 16),
            (AS3 uint*)((char*)kh + off), 16, 0, 0);
        __builtin_amdgcn_global_load_lds(
            (const AS1 uint*)((const char*)gl + off + lane * 16),
            (AS3 uint*)((char*)kl + off), 16, 0, 0);
    }
}

// ---- mask 64^3 -> 8^3 trilinear (degenerates to 2x2x2 box avg at offsets 3,4) ----
__global__ void k_m8(const float* __restrict__ mask, float* __restrict__ m8) {
    int b = blockIdx.x, sp = threadIdx.x;
    int a = sp >> 6, bb = (sp >> 3) & 7, cc = sp & 7;
    const float* mb = mask + (size_t)b * 262144;
    int i0 = 8 * a + 3, j0 = 8 * bb + 3, k0 = 8 * cc + 3;
    float s = 0.f;
#pragma unroll
    for (int di = 0; di < 2; ++di)
#pragma unroll
        for (int dj = 0; dj < 2; ++dj)
#pragma unroll
            for (int dk = 0; dk < 2; ++dk)
                s += mb[(i0 + di) * 4096 + (j0 + dj) * 64 + (k0 + dk)];
    m8[b * NS + sp] = s * 0.125f;
}

// ---- tok[b][s][d] = x[b][d][s]*m8[b][s] + pe[d][s]  (tiled transpose) ----
__global__ void k_tok(const float* __restrict__ x, const float* __restrict__ pe,
                      const float* __restrict__ m8, float* __restrict__ tok) {
    __shared__ float t[32][33];
    int b = blockIdx.z;
    int sp0 = blockIdx.x * 32, d0 = blockIdx.y * 32;
    int tx = threadIdx.x, ty = threadIdx.y;
#pragma unroll
    for (int i = 0; i < 4; ++i) {
        int d = d0 + ty + i * 8;
        int sp = sp0 + tx;
        float v = x[((size_t)(b * ND + d)) * NS + sp] * m8[b * NS + sp] + pe[(size_t)d * NS + sp];
        t[ty + i * 8][tx] = v;
    }
    __syncthreads();
#pragma unroll
    for (int i = 0; i < 4; ++i) {
        int sp = sp0 + ty + i * 8;
        int d = d0 + tx;
        tok[((size_t)(b * NS) + sp) * ND + d] = t[tx][ty + i * 8];
    }
}

// ---- mem_k fp32 -> bf16 hi/lo, PRE-SWIZZLED rows for global_load_lds staging ----
// Layout: row m stores its 8 16B-granules g at byte ((g*16) ^ ((m&7)<<4)) within
// the row's 128B. knn4's swizzled reads then match a LINEAR DMA copy.
__global__ void k_mksplit(const float* __restrict__ mk, ushort* __restrict__ mh,
                          ushort* __restrict__ ml) {
    int t = blockIdx.x * 256 + threadIdx.x;  // 262144 total
    int g = t & 7;
    int m = (t >> 3) & 8191;
    int b = t >> 16;
    const float* src = mk + ((size_t)(b * NM + m) * 64 + g * 8);
    float v[8];
#pragma unroll
    for (int j = 0; j < 8; ++j) v[j] = src[j];
    s16x8 hv, lv;
    split8(v, hv, lv);
    size_t rowbyte = (size_t)(b * NM + m) * 128;
    size_t off = rowbyte + (size_t)((g * 16) ^ ((m & 7) << 4));
    *(s16x8*)((char*)mh + off) = hv;
    *(s16x8*)((char*)ml + off) = lv;
}

// ---- split-bf16 MFMA GEMM: C = epi(A @ W + bias [+resid]), 3-pass hi/lo ----
template <int BM, int BN, int EPI>
__global__ __launch_bounds__(256) void k_gmm(
    const float* __restrict__ A, const float* __restrict__ W,
    const float* __restrict__ bias, const float* __restrict__ resid,
    float* __restrict__ C, int M, int N, int K) {
    constexpr int PAD = 40;
    constexpr int FM = BM / 32, FN = BN / 32;
    __shared__ __align__(16) ushort Ah[BM * PAD];
    __shared__ __align__(16) ushort Al[BM * PAD];
    __shared__ __align__(16) ushort Bh[BN * PAD];
    __shared__ __align__(16) ushort Bl[BN * PAD];
    int tid = threadIdx.x, lane = tid & 63, wvi = tid >> 6;
    int wr = wvi >> 1, wc = wvi & 1;
    int bn = blockIdx.x * BN, bm = blockIdx.y * BM;

    constexpr int FPTA = BM / 8;
    constexpr int TPRA = 32 / FPTA;
    int arow = tid / TPRA;
    int akoff = (tid % TPRA) * FPTA;
    const float* Ap = A + (size_t)(bm + arow) * K + akoff;

    constexpr int FPTB = BN / 8;
    int bkrow = tid >> 3;
    int bnoff = (tid & 7) * FPTB;
    const float* Wp = W + (size_t)bkrow * N + bn + bnoff;

    float abuf[FPTA], bbuf[FPTB];
#pragma unroll
    for (int j = 0; j < FPTA; j += 4) *(float4*)&abuf[j] = *(const float4*)(Ap + j);
#pragma unroll
    for (int j = 0; j < FPTB; j += 4) *(float4*)&bbuf[j] = *(const float4*)(Wp + j);

    f32x4 acc[FM][FN] = {};

    for (int k0 = 0; k0 < K; k0 += 32) {
#pragma unroll
        for (int g = 0; g < FPTA / 8; ++g) {
            s16x8 hv, lv;
            split8(&abuf[g * 8], hv, lv);
            *(s16x8*)&Ah[arow * PAD + akoff + g * 8] = hv;
            *(s16x8*)&Al[arow * PAD + akoff + g * 8] = lv;
        }
#pragma unroll
        for (int j = 0; j < FPTB; ++j) {
            ushort h, l;
            split1(bbuf[j], h, l);
            Bh[(bnoff + j) * PAD + bkrow] = h;
            Bl[(bnoff + j) * PAD + bkrow] = l;
        }
        __syncthreads();
        if (k0 + 32 < K) {
#pragma unroll
            for (int j = 0; j < FPTA; j += 4)
                *(float4*)&abuf[j] = *(const float4*)(Ap + k0 + 32 + j);
#pragma unroll
            for (int j = 0; j < FPTB; j += 4)
                *(float4*)&bbuf[j] = *(const float4*)(Wp + (size_t)(k0 + 32) * N + j);
        }
        s16x8 fah[FM], fal[FM], fbh[FN], fbl[FN];
        int kb = (lane >> 4) * 8;
#pragma unroll
        for (int fm = 0; fm < FM; ++fm) {
            int row = wr * (BM / 2) + fm * 16 + (lane & 15);
            fah[fm] = *(const s16x8*)&Ah[row * PAD + kb];
            fal[fm] = *(const s16x8*)&Al[row * PAD + kb];
        }
#pragma unroll
        for (int fn = 0; fn < FN; ++fn) {
            int row = wc * (BN / 2) + fn * 16 + (lane & 15);
            fbh[fn] = *(const s16x8*)&Bh[row * PAD + kb];
            fbl[fn] = *(const s16x8*)&Bl[row * PAD + kb];
        }
#pragma unroll
        for (int fm = 0; fm < FM; ++fm)
#pragma unroll
            for (int fn = 0; fn < FN; ++fn) {
                acc[fm][fn] = __builtin_amdgcn_mfma_f32_16x16x32_bf16(fah[fm], fbh[fn], acc[fm][fn], 0, 0, 0);
                acc[fm][fn] = __builtin_amdgcn_mfma_f32_16x16x32_bf16(fah[fm], fbl[fn], acc[fm][fn], 0, 0, 0);
                acc[fm][fn] = __builtin_amdgcn_mfma_f32_16x16x32_bf16(fal[fm], fbh[fn], acc[fm][fn], 0, 0, 0);
            }
        __syncthreads();
    }
#pragma unroll
    for (int fm = 0; fm < FM; ++fm) {
#pragma unroll
        for (int fn = 0; fn < FN; ++fn) {
            int n = bn + wc * (BN / 2) + fn * 16 + (lane & 15);
            float bb = bias[n];
#pragma unroll
            for (int r = 0; r < 4; ++r) {
                int m = bm + wr * (BM / 2) + fm * 16 + (lane >> 4) * 4 + r;
                float o = acc[fm][fn][r] + bb;
                if (EPI == 1) o = gelu_f(o);
                else if (EPI == 2) o += resid[(size_t)m * N + n];
                C[(size_t)m * N + n] = o;
            }
        }
    }
}

// ---- fused flash attention: per (b,h,32-row q tile) ----
__global__ __launch_bounds__(256) void k_attn(const float* __restrict__ qkv,
                                              float* __restrict__ ao) {
    __shared__ float qs[32][65];
    __shared__ float ks[64][65];
    __shared__ float sc[32][68];
    __shared__ float pm[32][8];
    __shared__ float Mrow[32], Srow[32], Arow[32];
    int s0 = blockIdx.x * 32, h = blockIdx.y, b = blockIdx.z;
    int tid = threadIdx.x, tx = tid & 15, ty = tid >> 4;
    const float* base = qkv + (size_t)b * NS * 1536;
#pragma unroll
    for (int i = 0; i < 8; ++i) {
        int idx = tid + i * 256;
        int r = idx >> 6, d = idx & 63;
        qs[r][d] = base[(size_t)(s0 + r) * 1536 + h * 64 + d] * 0.125f;
    }
    if (tid < 32) { Mrow[tid] = -FLT_MAX; Srow[tid] = 0.f; }
    float accp[2][4] = {};
    int rg = tid >> 3, gg = tid & 7;
    for (int c = 0; c < 8; ++c) {
        __syncthreads();
#pragma unroll
        for (int i = 0; i < 16; ++i) {
            int idx = tid + i * 256;
            int r = idx >> 6, d = idx & 63;
            ks[r][d] = base[(size_t)(c * 64 + r) * 1536 + 512 + h * 64 + d];
        }
        __syncthreads();
        float a00 = 0, a01 = 0, a02 = 0, a03 = 0, a10 = 0, a11 = 0, a12 = 0, a13 = 0;
#pragma unroll 8
        for (int d = 0; d < 64; ++d) {
            float q0 = qs[ty][d], q1 = qs[ty + 16][d];
            float k0 = ks[tx][d], k1 = ks[tx + 16][d], k2 = ks[tx + 32][d], k3 = ks[tx + 48][d];
            a00 += q0 * k0; a01 += q0 * k1; a02 += q0 * k2; a03 += q0 * k3;
            a10 += q1 * k0; a11 += q1 * k1; a12 += q1 * k2; a13 += q1 * k3;
        }
        sc[ty][tx] = a00; sc[ty][tx + 16] = a01; sc[ty][tx + 32] = a02; sc[ty][tx + 48] = a03;
        sc[ty + 16][tx] = a10; sc[ty + 16][tx + 16] = a11; sc[ty + 16][tx + 32] = a12; sc[ty + 16][tx + 48] = a13;
        __syncthreads();
        float lm = -FLT_MAX;
#pragma unroll
        for (int j = 0; j < 8; ++j) lm = fmaxf(lm, sc[rg][gg * 8 + j]);
        pm[rg][gg] = lm;
        __syncthreads();
        if (gg == 0) {
            float nm = Mrow[rg];
#pragma unroll
            for (int j = 0; j < 8; ++j) nm = fmaxf(nm, pm[rg][j]);
            Arow[rg] = __expf(Mrow[rg] - nm);
            Mrow[rg] = nm;
        }
        __syncthreads();
        float mr = Mrow[rg];
        float ssp = 0.f;
#pragma unroll
        for (int j = 0; j < 8; ++j) {
            float e = __expf(sc[rg][gg * 8 + j] - mr);
            sc[rg][gg * 8 + j] = e;
            ssp += e;
        }
        pm[rg][gg] = ssp;
        __syncthreads();
        if (gg == 0) {
            float s2 = 0.f;
#pragma unroll
            for (int j = 0; j < 8; ++j) s2 += pm[rg][j];
            Srow[rg] = Srow[rg] * Arow[rg] + s2;
        }
        float al0 = Arow[ty], al1 = Arow[ty + 16];
#pragma unroll
        for (int j = 0; j < 4; ++j) { accp[0][j] *= al0; accp[1][j] *= al1; }
        __syncthreads();
#pragma unroll
        for (int i = 0; i < 16; ++i) {
            int idx = tid + i * 256;
            int r = idx >> 6, d = idx & 63;
            ks[r][d] = base[(size_t)(c * 64 + r) * 1536 + 1024 + h * 64 + d];
        }
        __syncthreads();
#pragma unroll 8
        for (int kk = 0; kk < 64; ++kk) {
            float p0 = sc[ty][kk], p1 = sc[ty + 16][kk];
            float v0 = ks[kk][tx], v1 = ks[kk][tx + 16], v2 = ks[kk][tx + 32], v3 = ks[kk][tx + 48];
            accp[0][0] += p0 * v0; accp[0][1] += p0 * v1; accp[0][2] += p0 * v2; accp[0][3] += p0 * v3;
            accp[1][0] += p1 * v0; accp[1][1] += p1 * v1; accp[1][2] += p1 * v2; accp[1][3] += p1 * v3;
        }
    }
    __syncthreads();
    float inv0 = 1.0f / Srow[ty], inv1 = 1.0f / Srow[ty + 16];
    size_t o0 = ((size_t)(b * NS) + s0 + ty) * ND + h * 64;
    size_t o1 = ((size_t)(b * NS) + s0 + ty + 16) * ND + h * 64;
    ao[o0 + tx] = accp[0][0] * inv0;
    ao[o0 + tx + 16] = accp[0][1] * inv0;
    ao[o0 + tx + 32] = accp[0][2] * inv0;
    ao[o0 + tx + 48] = accp[0][3] * inv0;
    ao[o1 + tx] = accp[1][0] * inv1;
    ao[o1 + tx + 16] = accp[1][1] * inv1;
    ao[o1 + tx + 32] = accp[1][2] * inv1;
    ao[o1 + tx + 48] = accp[1][3] * inv1;
}

// ==== KNN v4c: threshold-append + rare shrink; K staged via global_load_lds ====
// grid (NS/4, NB): block = (b, 4 s) -> 32 queries (8h x 4s), 256 threads.
__global__ __launch_bounds__(256, 2) void k_knn4(
    const float* __restrict__ qkv, const ushort* __restrict__ mkh,
    const ushort* __restrict__ mkl, const float* __restrict__ mv,
    const float* __restrict__ gate, float* __restrict__ ao) {
    __shared__ __align__(16) char SM[76288];
    ushort* kh = (ushort*)SM;
    ushort* kl = (ushort*)(SM + 16384);
    float* cval = (float*)(SM + 32768);
    ushort* cidx = (ushort*)(SM + 61440);
    float* thrV = (float*)(SM + 75776);
    int* cnt = (int*)(SM + 75904);
    int* sflag = (int*)(SM + 76032);
    ushort* qh = (ushort*)(SM + 32768);  // prologue overlay (4KB)
    ushort* ql = (ushort*)(SM + 36864);  // prologue overlay (4KB)

    int b = blockIdx.y, s0 = blockIdx.x * 4;
    int tid = threadIdx.x, lane = tid & 63, wvi = tid >> 6;
    const ushort* mhb = mkh + (size_t)b * NM * 64;  // pre-swizzled rows
    const ushort* mlb = mkl + (size_t)b * NM * 64;

    // ---- prologue: stage q (scaled, split, swizzled) + DMA chunk 0 ----
    {
        int q = tid >> 3, dbase = (tid & 7) * 8;
        const float* src = &qkv[((size_t)(b * NS) + s0 + (q & 3)) * 1536 + (q >> 2) * 64 + dbase];
        float v[8];
#pragma unroll
        for (int j = 0; j < 8; ++j) v[j] = src[j] * 0.125f;
        s16x8 hv, lv;
        split8(v, hv, lv);
        int by = q * 128 + ((dbase * 2) ^ ((q & 7) << 4));
        *(s16x8*)((char*)qh + by) = hv;
        *(s16x8*)((char*)ql + by) = lv;
    }
    stage_dma(mhb, mlb, kh, kl, wvi, lane);  // chunk 0 (drained by barrier)
    __syncthreads();  // q staged + chunk 0 landed
    // hoist q fragments (chunk-invariant)
    s16x8 fqh[2][2], fql[2][2];  // [fq][kstep]
#pragma unroll
    for (int fq = 0; fq < 2; ++fq)
#pragma unroll
        for (int ks = 0; ks < 2; ++ks) {
            int row = fq * 16 + (lane & 15);
            int kb2 = (ks * 32 + (lane >> 4) * 8) * 2;
            int by = row * 128 + (kb2 ^ ((row & 7) << 4));
            fqh[fq][ks] = *(const s16x8*)((const char*)qh + by);
            fql[fq][ks] = *(const s16x8*)((const char*)ql + by);
        }
    if (tid < 32) { cnt[tid] = 0; thrV[tid] = -FLT_MAX; }
    if (tid == 0) *sflag = 0;

    int qbase4 = (lane >> 4) * 4;  // C-frag row group

    for (int c = 0; c < NCC; ++c) {
        __syncthreads();  // A: k[c] ready (drains DMA); cnt/thr/flag consistent
        // threshold cache for this thread's 8 queries
        float thc[2][4];
#pragma unroll
        for (int fq = 0; fq < 2; ++fq)
#pragma unroll
            for (int r = 0; r < 4; ++r) thc[fq][r] = thrV[fq * 16 + qbase4 + r];

        // ---- sims: 3-pass split-bf16 MFMA; wave owns 32 m's (2 frags) ----
        f32x4 acc[2][2] = {};  // [fq][fm]
#pragma unroll
        for (int ks = 0; ks < 2; ++ks) {
            int kb2 = (ks * 32 + (lane >> 4) * 8) * 2;
#pragma unroll
            for (int fm = 0; fm < 2; ++fm) {
                int row = wvi * 32 + fm * 16 + (lane & 15);
                int by = row * 128 + (kb2 ^ ((row & 7) << 4));
                s16x8 kh8 = *(const s16x8*)((const char*)kh + by);
                s16x8 kl8 = *(const s16x8*)((const char*)kl + by);
#pragma unroll
                for (int fq = 0; fq < 2; ++fq) {
                    acc[fq][fm] = __builtin_amdgcn_mfma_f32_16x16x32_bf16(fqh[fq][ks], kh8, acc[fq][fm], 0, 0, 0);
                    acc[fq][fm] = __builtin_amdgcn_mfma_f32_16x16x32_bf16(fqh[fq][ks], kl8, acc[fq][fm], 0, 0, 0);
                    acc[fq][fm] = __builtin_amdgcn_mfma_f32_16x16x32_bf16(fql[fq][ks], kh8, acc[fq][fm], 0, 0, 0);
                }
            }
        }

        // ---- appends: unordered, threshold-gated; eager shrink flag ----
#pragma unroll
        for (int fq = 0; fq < 2; ++fq)
#pragma unroll
            for (int fm = 0; fm < 2; ++fm)
#pragma unroll
                for (int r = 0; r < 4; ++r) {
                    float v = acc[fq][fm][r];
                    if (v >= thc[fq][r]) {
                        int q = fq * 16 + qbase4 + r;
                        int pos = atomicAdd(&cnt[q], 1);
                        if (pos < CAPB) {
                            cval[q * CAPB + pos] = v;
                            cidx[q * CAPB + pos] = (ushort)(c * KCC + wvi * 32 + fm * 16 + (lane & 15));
                        }
                        if (pos == TRIG) *sflag = 1;
                    }
                }
        __syncthreads();  // B: appends done; all kh/kl reads done

        // DMA next chunk into kh/kl (async; drained by next barrier A)
        if (c + 1 < NCC) {
            size_t ro = (size_t)(c + 1) * KCC * 64;
            stage_dma(mhb + ro, mlb + ro, kh, kl, wvi, lane);
        }

        if (*sflag) {  // block-uniform
#pragma unroll 1
            for (int qq = 0; qq < 8; ++qq) {
                int q = wvi * 8 + qq;
                int n = cnt[q];
                if (n <= TRIG) continue;
                shrink32(cval, cidx, q, n, lane, &thrV[q]);
                if (lane == 0) cnt[q] = 32;
            }
            __syncthreads();  // C: shrink done
            if (tid == 0) *sflag = 0;
        }
    }

    // ---- final shrink (unconditional, exact top-32 sorted desc) ----
#pragma unroll 1
    for (int qq = 0; qq < 8; ++qq) {
        int q = wvi * 8 + qq;
        shrink32(cval, cidx, q, cnt[q], lane, nullptr);
    }
    __syncthreads();

    // ---- softmax weights (slot 0 = max by construction) ----
    if (tid < 32) {
        int q = tid;
        float mx = cval[q * CAPB];
        float es[32];
        float ssum = 0.f;
#pragma unroll
        for (int j = 0; j < 32; ++j) { es[j] = __expf(cval[q * CAPB + j] - mx); ssum += es[j]; }
        float inv = 1.0f / ssum;
#pragma unroll
        for (int j = 0; j < 32; ++j) cval[q * CAPB + j] = es[j] * inv;
    }
    __syncthreads();

    // ---- gather mem_v and blend into ao: 8 threads/query, 8 d each ----
    {
        int q = tid >> 3, dseg = (tid & 7) * 8;
        int h = q >> 2, si = q & 3;
        float r0x = 0, r0y = 0, r0z = 0, r0w = 0, r1x = 0, r1y = 0, r1z = 0, r1w = 0;
        const float* vb = mv + (size_t)b * NM * NHD;
        for (int j = 0; j < 32; ++j) {
            float w = cval[q * CAPB + j];
            int idx = (int)cidx[q * CAPB + j];
            const float* row = vb + (size_t)idx * NHD + dseg;
            float4 v0 = *(const float4*)(row);
            float4 v1 = *(const float4*)(row + 4);
            r0x += w * v0.x; r0y += w * v0.y; r0z += w * v0.z; r0w += w * v0.w;
            r1x += w * v1.x; r1y += w * v1.y; r1z += w * v1.z; r1w += w * v1.w;
        }
        float g = 1.0f / (1.0f + __expf(-gate[h]));
        float omg = 1.0f - g;
        float* aop = ao + ((size_t)(b * NS) + s0 + si) * ND + h * 64 + dseg;
        float rr[8] = {r0x, r0y, r0z, r0w, r1x, r1y, r1z, r1w};
#pragma unroll
        for (int k = 0; k < 8; ++k) aop[k] = aop[k] * omg + rr[k] * g;
    }
}

// ---- LayerNorm over D=512 per row ----
__global__ __launch_bounds__(256) void k_ln(const float* __restrict__ X,
                                            const float* __restrict__ gam,
                                            const float* __restrict__ bet,
                                            float* __restrict__ Y) {
    __shared__ float red[4];
    __shared__ float sm, sv;
    int r = blockIdx.x, tid = threadIdx.x;
    const float* xr = X + (size_t)r * ND;
    float x0 = xr[tid], x1 = xr[tid + 256];
    float s = x0 + x1;
    for (int off = 32; off; off >>= 1) s += __shfl_down(s, off);
    if ((tid & 63) == 0) red[tid >> 6] = s;
    __syncthreads();
    if (tid == 0) sm = (red[0] + red[1] + red[2] + red[3]) * (1.0f / 512.0f);
    __syncthreads();
    float m = sm;
    float d0 = x0 - m, d1 = x1 - m;
    float vs = d0 * d0 + d1 * d1;
    for (int off = 32; off; off >>= 1) vs += __shfl_down(vs, off);
    if ((tid & 63) == 0) red[tid >> 6] = vs;
    __syncthreads();
    if (tid == 0) sv = rsqrtf((red[0] + red[1] + red[2] + red[3]) * (1.0f / 512.0f) + 1e-5f);
    __syncthreads();
    float rstd = sv;
    Y[(size_t)r * ND + tid] = d0 * rstd * gam[tid] + bet[tid];
    Y[(size_t)r * ND + tid + 256] = d1 * rstd * gam[tid + 256] + bet[tid + 256];
}

// ---- mean pool over S ----
__global__ void k_pool(const float* __restrict__ tok, float* __restrict__ pooled) {
    int b = blockIdx.x, d = threadIdx.x;
    float s = 0.f;
    for (int sp = 0; sp < NS; ++sp) s += tok[((size_t)(b * NS) + sp) * ND + d];
    pooled[b * ND + d] = s * (1.0f / 512.0f);
}

__global__ void k_fc1(const float* __restrict__ pooled, const float* __restrict__ w,
                      const float* __restrict__ bias, float* __restrict__ o1) {
    int id = blockIdx.x * 256 + threadIdx.x;  // 4096
    int b = id >> 10, j = id & 1023;
    float acc = bias[j];
    for (int d = 0; d < ND; ++d) acc += pooled[b * ND + d] * w[(size_t)d * NMLP + j];
    o1[id] = gelu_f(acc);
}

__global__ void k_fc2(const float* __restrict__ o1, const float* __restrict__ w,
                      const float* __restrict__ bias, float* __restrict__ out) {
    int id = blockIdx.x * 256 + threadIdx.x;
    if (id >= NB * NC) return;
    int b = id / NC, c = id % NC;
    float acc = bias[c];
    for (int k = 0; k < NMLP; ++k) acc += o1[b * NMLP + k] * w[(size_t)k * NC + c];
    out[id] = acc;
}

extern "C" void kernel_launch(void* const* d_in, const int* in_sizes, int n_in,
                              void* d_out, int out_size, void* d_ws, size_t ws_size,
                              hipStream_t stream) {
    const float* x    = (const float*)d_in[0];
    const float* mask = (const float*)d_in[1];
    const float* pe   = (const float*)d_in[2];
    const float* Wqkv = (const float*)d_in[3];
    const float* bqkv = (const float*)d_in[4];
    const float* Wo   = (const float*)d_in[5];
    const float* bo   = (const float*)d_in[6];
    const float* ln1g = (const float*)d_in[7];
    const float* ln1b = (const float*)d_in[8];
    const float* W1   = (const float*)d_in[9];
    const float* b1   = (const float*)d_in[10];
    const float* W2   = (const float*)d_in[11];
    const float* b2   = (const float*)d_in[12];
    const float* ln2g = (const float*)d_in[13];
    const float* ln2b = (const float*)d_in[14];
    const float* gate = (const float*)d_in[15];
    const float* memk = (const float*)d_in[16];
    const float* memv = (const float*)d_in[17];
    const float* fc1w = (const float*)d_in[18];
    const float* fc1b = (const float*)d_in[19];
    const float* fc2w = (const float*)d_in[20];
    const float* fc2b = (const float*)d_in[21];
    float* out = (float*)d_out;

    float* ws = (float*)d_ws;
    float* m8     = ws;                       // 2048
    ushort* mkh   = (ushort*)(m8 + 2048);     // 2097152 ushort (pre-swizzled rows)
    ushort* mkl   = mkh + 2097152;            // 2097152 ushort
    float* tok    = (float*)(mkl + 2097152);  // 1048576
    float* qkv    = tok + 1048576;            // 3145728
    float* ao     = qkv + 3145728;            // 1048576
    float* ybuf   = ao + 1048576;             // 1048576
    float* ff1    = ybuf + 1048576;           // 4194304
    float* pooled = ff1 + 4194304;            // 2048
    float* o1     = pooled + 2048;            // 4096

    k_m8<<<NB, 512, 0, stream>>>(mask, m8);
    k_mksplit<<<1024, 256, 0, stream>>>(memk, mkh, mkl);
    k_tok<<<dim3(16, 16, NB), dim3(32, 8), 0, stream>>>(x, pe, m8, tok);

    for (int l = 0; l < NL; ++l) {
        k_gmm<128, 128, 0><<<dim3(12, 16), 256, 0, stream>>>(
            tok, Wqkv + (size_t)l * 512 * 1536, bqkv + l * 1536, nullptr, qkv, 2048, 1536, 512);
        k_attn<<<dim3(16, NH, NB), 256, 0, stream>>>(qkv, ao);
        if (l == 0)
            k_knn4<<<dim3(NS / 4, NB), 256, 0, stream>>>(qkv, mkh, mkl, memv, gate, ao);
        k_gmm<64, 64, 2><<<dim3(8, 32), 256, 0, stream>>>(
            ao, Wo + (size_t)l * 512 * 512, bo + l * 512, tok, ybuf, 2048, 512, 512);
        k_ln<<<2048, 256, 0, stream>>>(ybuf, ln1g + l * 512, ln1b + l * 512, tok);
        k_gmm<128, 128, 1><<<dim3(16, 16), 256, 0, stream>>>(
            tok, W1 + (size_t)l * 512 * 2048, b1 + l * 2048, nullptr, ff1, 2048, 2048, 512);
        k_gmm<64, 64, 2><<<dim3(8, 32), 256, 0, stream>>>(
            ff1, W2 + (size_t)l * 2048 * 512, b2 + l * 512, tok, ybuf, 2048, 512, 2048);
        k_ln<<<2048, 256, 0, stream>>>(ybuf, ln2g + l * 512, ln2b + l * 512, tok);
    }

    k_pool<<<NB, 512, 0, stream>>>(tok, pooled);
    k_fc1<<<16, 256, 0, stream>>>(pooled, fc1w, fc1b, o1);
    k_fc2<<<2, 256, 0, stream>>>(o1, fc2w, fc2b, out);
}

// Round 8
// 2267.978 us; speedup vs baseline: 1.2825x; 1.2109x over previous
//
#include <hip/hip_runtime.h>
#include <hip/hip_bf16.h>
#include <float.h>
#include <math.h>

// Problem constants
#define NB 4
#define ND 512
#define NS 512
#define NH 8
#define NHD 64
#define NM 8192
#define NL 6
#define NFF 2048
#define NMLP 1024
#define NC 117

// knn4 params
#define KCC 128               // m's per chunk
#define NCC (NM / KCC)        // 64 chunks
#define CAPB 224              // buffer capacity per query
#define TRIG 96               // shrink trigger: (TRIG-1) + KCC < CAPB -> no overflow

#define AS1 __attribute__((address_space(1)))
#define AS3 __attribute__((address_space(3)))

typedef __attribute__((ext_vector_type(8))) short s16x8;
typedef __attribute__((ext_vector_type(4))) float f32x4;

__device__ __forceinline__ float gelu_f(float x) {
    return 0.5f * x * (1.0f + erff(x * 0.70710678118654752440f));
}

__device__ __forceinline__ ushort f2bf_rne(float x) {
    uint u = __float_as_uint(x);
    uint r = u + 0x7FFFu + ((u >> 16) & 1u);
    return (ushort)(r >> 16);
}
__device__ __forceinline__ float bf2f(ushort h) { return __uint_as_float(((uint)h) << 16); }
__device__ __forceinline__ void split1(float x, ushort& h, ushort& l) {
    h = f2bf_rne(x);
    float r = x - bf2f(h);
    l = f2bf_rne(r);
}
__device__ __forceinline__ void split8(const float* v, s16x8& hv, s16x8& lv) {
#pragma unroll
    for (int j = 0; j < 8; ++j) {
        ushort h, l;
        split1(v[j], h, l);
        hv[j] = (short)h;
        lv[j] = (short)l;
    }
}

// sortable key: (value desc, index asc) -> larger key wins; valid keys are nonzero
__device__ __forceinline__ unsigned long long packkey(float v, int idx) {
    uint u = __float_as_uint(v);
    u = u ^ (((int)u < 0) ? 0xFFFFFFFFu : 0x80000000u);
    return (((unsigned long long)u) << 13) | (unsigned long long)(8191 - idx);
}
__device__ __forceinline__ float keyval(unsigned long long K) {
    uint vb = (uint)(K >> 13);
    uint orig = (vb & 0x80000000u) ? (vb ^ 0x80000000u) : ~vb;
    return __uint_as_float(orig);
}

// Cheap exact top-32 retain: binary-search the 32nd-largest key, then
// ballot-compact the exactly-32 entries with key >= K32 into slots 0..31
// (UNSORTED). Static register indexing only (rule #20).
__device__ __forceinline__ void shrink_cheap(float* __restrict__ cval,
                                             ushort* __restrict__ cidx,
                                             int q, int n, int lane,
                                             float* __restrict__ thrOut) {
    if (n < 32) return;  // unreachable after chunk 0; defensive
    int j0 = lane, j1 = lane + 64, j2 = lane + 128, j3 = lane + 192;
    bool o0 = j0 < n, o1 = j1 < n, o2 = j2 < n, o3 = j3 < n;
    float v0 = o0 ? cval[q * CAPB + j0] : 0.f;
    float v1 = o1 ? cval[q * CAPB + j1] : 0.f;
    float v2 = o2 ? cval[q * CAPB + j2] : 0.f;
    float v3 = o3 ? cval[q * CAPB + j3] : 0.f;
    ushort i0 = o0 ? cidx[q * CAPB + j0] : 0;
    ushort i1 = o1 ? cidx[q * CAPB + j1] : 0;
    ushort i2 = o2 ? cidx[q * CAPB + j2] : 0;
    ushort i3 = o3 ? cidx[q * CAPB + j3] : 0;
    unsigned long long k0 = o0 ? packkey(v0, (int)i0) : 0ULL;
    unsigned long long k1 = o1 ? packkey(v1, (int)i1) : 0ULL;
    unsigned long long k2 = o2 ? packkey(v2, (int)i2) : 0ULL;
    unsigned long long k3 = o3 ? packkey(v3, (int)i3) : 0ULL;
    // binary search largest K with count(key >= K) >= 32  (keys unique)
    unsigned long long lo = 0, hi = (1ULL << 45) - 1;
    while (lo < hi) {
        unsigned long long mid = (lo + hi + 1) >> 1;
        int c = (int)(k0 >= mid) + (int)(k1 >= mid) + (int)(k2 >= mid) + (int)(k3 >= mid);
#pragma unroll
        for (int off = 32; off; off >>= 1) c += __shfl_xor(c, off);
        if (c >= 32) lo = mid;
        else hi = mid - 1;
    }
    unsigned long long K = lo;
    unsigned long long lanemask = (1ULL << lane) - 1;
    int base = 0;
    {
        unsigned long long m = __ballot(k0 >= K);
        if (k0 >= K) { int p = base + (int)__popcll(m & lanemask); cval[q * CAPB + p] = v0; cidx[q * CAPB + p] = i0; }
        base += (int)__popcll(m);
    }
    {
        unsigned long long m = __ballot(k1 >= K);
        if (k1 >= K) { int p = base + (int)__popcll(m & lanemask); cval[q * CAPB + p] = v1; cidx[q * CAPB + p] = i1; }
        base += (int)__popcll(m);
    }
    {
        unsigned long long m = __ballot(k2 >= K);
        if (k2 >= K) { int p = base + (int)__popcll(m & lanemask); cval[q * CAPB + p] = v2; cidx[q * CAPB + p] = i2; }
        base += (int)__popcll(m);
    }
    {
        unsigned long long m = __ballot(k3 >= K);
        if (k3 >= K) { int p = base + (int)__popcll(m & lanemask); cval[q * CAPB + p] = v3; cidx[q * CAPB + p] = i3; }
        base += (int)__popcll(m);
    }
    if (thrOut && lane == 0) *thrOut = keyval(K);
}

// async DMA of one 16KB-per-buffer chunk (128 rows x 128B) into kh/kl.
// Sources are PRE-SWIZZLED, so dest is linear (rule #21). Drained by next barrier.
__device__ __forceinline__ void stage_dma(const ushort* __restrict__ gh,
                                          const ushort* __restrict__ gl,
                                          ushort* kh, ushort* kl,
                                          int wvi, int lane) {
#pragma unroll
    for (int i = 0; i < 4; ++i) {
        int off = (wvi * 4 + i) * 1024;  // bytes
        __builtin_amdgcn_global_load_lds(
            (const AS1 uint*)((const char*)gh + off + lane * 16),
            (AS3 uint*)((char*)kh + off), 16, 0, 0);
        __builtin_amdgcn_global_load_lds(
            (const AS1 uint*)((const char*)gl + off + lane * 16),
            (AS3 uint*)((char*)kl + off), 16, 0, 0);
    }
}

// ---- mask 64^3 -> 8^3 trilinear (degenerates to 2x2x2 box avg at offsets 3,4) ----
__global__ void k_m8(const float* __restrict__ mask, float* __restrict__ m8) {
    int b = blockIdx.x, sp = threadIdx.x;
    int a = sp >> 6, bb = (sp >> 3) & 7, cc = sp & 7;
    const float* mb = mask + (size_t)b * 262144;
    int i0 = 8 * a + 3, j0 = 8 * bb + 3, k0 = 8 * cc + 3;
    float s = 0.f;
#pragma unroll
    for (int di = 0; di < 2; ++di)
#pragma unroll
        for (int dj = 0; dj < 2; ++dj)
#pragma unroll
            for (int dk = 0; dk < 2; ++dk)
                s += mb[(i0 + di) * 4096 + (j0 + dj) * 64 + (k0 + dk)];
    m8[b * NS + sp] = s * 0.125f;
}

// ---- tok[b][s][d] = x[b][d][s]*m8[b][s] + pe[d][s]  (tiled transpose) ----
__global__ void k_tok(const float* __restrict__ x, const float* __restrict__ pe,
                      const float* __restrict__ m8, float* __restrict__ tok) {
    __shared__ float t[32][33];
    int b = blockIdx.z;
    int sp0 = blockIdx.x * 32, d0 = blockIdx.y * 32;
    int tx = threadIdx.x, ty = threadIdx.y;
#pragma unroll
    for (int i = 0; i < 4; ++i) {
        int d = d0 + ty + i * 8;
        int sp = sp0 + tx;
        float v = x[((size_t)(b * ND + d)) * NS + sp] * m8[b * NS + sp] + pe[(size_t)d * NS + sp];
        t[ty + i * 8][tx] = v;
    }
    __syncthreads();
#pragma unroll
    for (int i = 0; i < 4; ++i) {
        int sp = sp0 + ty + i * 8;
        int d = d0 + tx;
        tok[((size_t)(b * NS) + sp) * ND + d] = t[tx][ty + i * 8];
    }
}

// ---- mem_k fp32 -> bf16 hi/lo, PRE-SWIZZLED rows for global_load_lds staging ----
__global__ void k_mksplit(const float* __restrict__ mk, ushort* __restrict__ mh,
                          ushort* __restrict__ ml) {
    int t = blockIdx.x * 256 + threadIdx.x;  // 262144 total
    int g = t & 7;
    int m = (t >> 3) & 8191;
    int b = t >> 16;
    const float* src = mk + ((size_t)(b * NM + m) * 64 + g * 8);
    float v[8];
#pragma unroll
    for (int j = 0; j < 8; ++j) v[j] = src[j];
    s16x8 hv, lv;
    split8(v, hv, lv);
    size_t rowbyte = (size_t)(b * NM + m) * 128;
    size_t off = rowbyte + (size_t)((g * 16) ^ ((m & 7) << 4));
    *(s16x8*)((char*)mh + off) = hv;
    *(s16x8*)((char*)ml + off) = lv;
}

// ---- split-bf16 MFMA GEMM: C = epi(A @ W + bias [+resid]), 3-pass hi/lo ----
template <int BM, int BN, int EPI>
__global__ __launch_bounds__(256) void k_gmm(
    const float* __restrict__ A, const float* __restrict__ W,
    const float* __restrict__ bias, const float* __restrict__ resid,
    float* __restrict__ C, int M, int N, int K) {
    constexpr int PAD = 40;
    constexpr int FM = BM / 32, FN = BN / 32;
    __shared__ __align__(16) ushort Ah[BM * PAD];
    __shared__ __align__(16) ushort Al[BM * PAD];
    __shared__ __align__(16) ushort Bh[BN * PAD];
    __shared__ __align__(16) ushort Bl[BN * PAD];
    int tid = threadIdx.x, lane = tid & 63, wvi = tid >> 6;
    int wr = wvi >> 1, wc = wvi & 1;
    int bn = blockIdx.x * BN, bm = blockIdx.y * BM;

    constexpr int FPTA = BM / 8;
    constexpr int TPRA = 32 / FPTA;
    int arow = tid / TPRA;
    int akoff = (tid % TPRA) * FPTA;
    const float* Ap = A + (size_t)(bm + arow) * K + akoff;

    constexpr int FPTB = BN / 8;
    int bkrow = tid >> 3;
    int bnoff = (tid & 7) * FPTB;
    const float* Wp = W + (size_t)bkrow * N + bn + bnoff;

    float abuf[FPTA], bbuf[FPTB];
#pragma unroll
    for (int j = 0; j < FPTA; j += 4) *(float4*)&abuf[j] = *(const float4*)(Ap + j);
#pragma unroll
    for (int j = 0; j < FPTB; j += 4) *(float4*)&bbuf[j] = *(const float4*)(Wp + j);

    f32x4 acc[FM][FN] = {};

    for (int k0 = 0; k0 < K; k0 += 32) {
#pragma unroll
        for (int g = 0; g < FPTA / 8; ++g) {
            s16x8 hv, lv;
            split8(&abuf[g * 8], hv, lv);
            *(s16x8*)&Ah[arow * PAD + akoff + g * 8] = hv;
            *(s16x8*)&Al[arow * PAD + akoff + g * 8] = lv;
        }
#pragma unroll
        for (int j = 0; j < FPTB; ++j) {
            ushort h, l;
            split1(bbuf[j], h, l);
            Bh[(bnoff + j) * PAD + bkrow] = h;
            Bl[(bnoff + j) * PAD + bkrow] = l;
        }
        __syncthreads();
        if (k0 + 32 < K) {
#pragma unroll
            for (int j = 0; j < FPTA; j += 4)
                *(float4*)&abuf[j] = *(const float4*)(Ap + k0 + 32 + j);
#pragma unroll
            for (int j = 0; j < FPTB; j += 4)
                *(float4*)&bbuf[j] = *(const float4*)(Wp + (size_t)(k0 + 32) * N + j);
        }
        s16x8 fah[FM], fal[FM], fbh[FN], fbl[FN];
        int kb = (lane >> 4) * 8;
#pragma unroll
        for (int fm = 0; fm < FM; ++fm) {
            int row = wr * (BM / 2) + fm * 16 + (lane & 15);
            fah[fm] = *(const s16x8*)&Ah[row * PAD + kb];
            fal[fm] = *(const s16x8*)&Al[row * PAD + kb];
        }
#pragma unroll
        for (int fn = 0; fn < FN; ++fn) {
            int row = wc * (BN / 2) + fn * 16 + (lane & 15);
            fbh[fn] = *(const s16x8*)&Bh[row * PAD + kb];
            fbl[fn] = *(const s16x8*)&Bl[row * PAD + kb];
        }
#pragma unroll
        for (int fm = 0; fm < FM; ++fm)
#pragma unroll
            for (int fn = 0; fn < FN; ++fn) {
                acc[fm][fn] = __builtin_amdgcn_mfma_f32_16x16x32_bf16(fah[fm], fbh[fn], acc[fm][fn], 0, 0, 0);
                acc[fm][fn] = __builtin_amdgcn_mfma_f32_16x16x32_bf16(fah[fm], fbl[fn], acc[fm][fn], 0, 0, 0);
                acc[fm][fn] = __builtin_amdgcn_mfma_f32_16x16x32_bf16(fal[fm], fbh[fn], acc[fm][fn], 0, 0, 0);
            }
        __syncthreads();
    }
#pragma unroll
    for (int fm = 0; fm < FM; ++fm) {
#pragma unroll
        for (int fn = 0; fn < FN; ++fn) {
            int n = bn + wc * (BN / 2) + fn * 16 + (lane & 15);
            float bb = bias[n];
#pragma unroll
            for (int r = 0; r < 4; ++r) {
                int m = bm + wr * (BM / 2) + fm * 16 + (lane >> 4) * 4 + r;
                float o = acc[fm][fn][r] + bb;
                if (EPI == 1) o = gelu_f(o);
                else if (EPI == 2) o += resid[(size_t)m * N + n];
                C[(size_t)m * N + n] = o;
            }
        }
    }
}

// ---- fused flash attention: per (b,h,32-row q tile) ----
__global__ __launch_bounds__(256) void k_attn(const float* __restrict__ qkv,
                                              float* __restrict__ ao) {
    __shared__ float qs[32][65];
    __shared__ float ks[64][65];
    __shared__ float sc[32][68];
    __shared__ float pm[32][8];
    __shared__ float Mrow[32], Srow[32], Arow[32];
    int s0 = blockIdx.x * 32, h = blockIdx.y, b = blockIdx.z;
    int tid = threadIdx.x, tx = tid & 15, ty = tid >> 4;
    const float* base = qkv + (size_t)b * NS * 1536;
#pragma unroll
    for (int i = 0; i < 8; ++i) {
        int idx = tid + i * 256;
        int r = idx >> 6, d = idx & 63;
        qs[r][d] = base[(size_t)(s0 + r) * 1536 + h * 64 + d] * 0.125f;
    }
    if (tid < 32) { Mrow[tid] = -FLT_MAX; Srow[tid] = 0.f; }
    float accp[2][4] = {};
    int rg = tid >> 3, gg = tid & 7;
    for (int c = 0; c < 8; ++c) {
        __syncthreads();
#pragma unroll
        for (int i = 0; i < 16; ++i) {
            int idx = tid + i * 256;
            int r = idx >> 6, d = idx & 63;
            ks[r][d] = base[(size_t)(c * 64 + r) * 1536 + 512 + h * 64 + d];
        }
        __syncthreads();
        float a00 = 0, a01 = 0, a02 = 0, a03 = 0, a10 = 0, a11 = 0, a12 = 0, a13 = 0;
#pragma unroll 8
        for (int d = 0; d < 64; ++d) {
            float q0 = qs[ty][d], q1 = qs[ty + 16][d];
            float k0 = ks[tx][d], k1 = ks[tx + 16][d], k2 = ks[tx + 32][d], k3 = ks[tx + 48][d];
            a00 += q0 * k0; a01 += q0 * k1; a02 += q0 * k2; a03 += q0 * k3;
            a10 += q1 * k0; a11 += q1 * k1; a12 += q1 * k2; a13 += q1 * k3;
        }
        sc[ty][tx] = a00; sc[ty][tx + 16] = a01; sc[ty][tx + 32] = a02; sc[ty][tx + 48] = a03;
        sc[ty + 16][tx] = a10; sc[ty + 16][tx + 16] = a11; sc[ty + 16][tx + 32] = a12; sc[ty + 16][tx + 48] = a13;
        __syncthreads();
        float lm = -FLT_MAX;
#pragma unroll
        for (int j = 0; j < 8; ++j) lm = fmaxf(lm, sc[rg][gg * 8 + j]);
        pm[rg][gg] = lm;
        __syncthreads();
        if (gg == 0) {
            float nm = Mrow[rg];
#pragma unroll
            for (int j = 0; j < 8; ++j) nm = fmaxf(nm, pm[rg][j]);
            Arow[rg] = __expf(Mrow[rg] - nm);
            Mrow[rg] = nm;
        }
        __syncthreads();
        float mr = Mrow[rg];
        float ssp = 0.f;
#pragma unroll
        for (int j = 0; j < 8; ++j) {
            float e = __expf(sc[rg][gg * 8 + j] - mr);
            sc[rg][gg * 8 + j] = e;
            ssp += e;
        }
        pm[rg][gg] = ssp;
        __syncthreads();
        if (gg == 0) {
            float s2 = 0.f;
#pragma unroll
            for (int j = 0; j < 8; ++j) s2 += pm[rg][j];
            Srow[rg] = Srow[rg] * Arow[rg] + s2;
        }
        float al0 = Arow[ty], al1 = Arow[ty + 16];
#pragma unroll
        for (int j = 0; j < 4; ++j) { accp[0][j] *= al0; accp[1][j] *= al1; }
        __syncthreads();
#pragma unroll
        for (int i = 0; i < 16; ++i) {
            int idx = tid + i * 256;
            int r = idx >> 6, d = idx & 63;
            ks[r][d] = base[(size_t)(c * 64 + r) * 1536 + 1024 + h * 64 + d];
        }
        __syncthreads();
#pragma unroll 8
        for (int kk = 0; kk < 64; ++kk) {
            float p0 = sc[ty][kk], p1 = sc[ty + 16][kk];
            float v0 = ks[kk][tx], v1 = ks[kk][tx + 16], v2 = ks[kk][tx + 32], v3 = ks[kk][tx + 48];
            accp[0][0] += p0 * v0; accp[0][1] += p0 * v1; accp[0][2] += p0 * v2; accp[0][3] += p0 * v3;
            accp[1][0] += p1 * v0; accp[1][1] += p1 * v1; accp[1][2] += p1 * v2; accp[1][3] += p1 * v3;
        }
    }
    __syncthreads();
    float inv0 = 1.0f / Srow[ty], inv1 = 1.0f / Srow[ty + 16];
    size_t o0 = ((size_t)(b * NS) + s0 + ty) * ND + h * 64;
    size_t o1 = ((size_t)(b * NS) + s0 + ty + 16) * ND + h * 64;
    ao[o0 + tx] = accp[0][0] * inv0;
    ao[o0 + tx + 16] = accp[0][1] * inv0;
    ao[o0 + tx + 32] = accp[0][2] * inv0;
    ao[o0 + tx + 48] = accp[0][3] * inv0;
    ao[o1 + tx] = accp[1][0] * inv1;
    ao[o1 + tx + 16] = accp[1][1] * inv1;
    ao[o1 + tx + 32] = accp[1][2] * inv1;
    ao[o1 + tx + 48] = accp[1][3] * inv1;
}

// ==== KNN v4d: threshold-append + shrink-ALL events w/ cheap binary-search shrink ====
// grid (NS/4, NB): block = (b, 4 s) -> 32 queries (8h x 4s), 256 threads.
__global__ __launch_bounds__(256, 2) void k_knn4(
    const float* __restrict__ qkv, const ushort* __restrict__ mkh,
    const ushort* __restrict__ mkl, const float* __restrict__ mv,
    const float* __restrict__ gate, float* __restrict__ ao) {
    __shared__ __align__(16) char SM[76288];
    ushort* kh = (ushort*)SM;
    ushort* kl = (ushort*)(SM + 16384);
    float* cval = (float*)(SM + 32768);
    ushort* cidx = (ushort*)(SM + 61440);
    float* thrV = (float*)(SM + 75776);
    int* cnt = (int*)(SM + 75904);
    int* sflag = (int*)(SM + 76032);
    ushort* qh = (ushort*)(SM + 32768);  // prologue overlay (4KB)
    ushort* ql = (ushort*)(SM + 36864);  // prologue overlay (4KB)

    int b = blockIdx.y, s0 = blockIdx.x * 4;
    int tid = threadIdx.x, lane = tid & 63, wvi = tid >> 6;
    const ushort* mhb = mkh + (size_t)b * NM * 64;  // pre-swizzled rows
    const ushort* mlb = mkl + (size_t)b * NM * 64;

    // ---- prologue: stage q (scaled, split, swizzled) + DMA chunk 0 ----
    {
        int q = tid >> 3, dbase = (tid & 7) * 8;
        const float* src = &qkv[((size_t)(b * NS) + s0 + (q & 3)) * 1536 + (q >> 2) * 64 + dbase];
        float v[8];
#pragma unroll
        for (int j = 0; j < 8; ++j) v[j] = src[j] * 0.125f;
        s16x8 hv, lv;
        split8(v, hv, lv);
        int by = q * 128 + ((dbase * 2) ^ ((q & 7) << 4));
        *(s16x8*)((char*)qh + by) = hv;
        *(s16x8*)((char*)ql + by) = lv;
    }
    stage_dma(mhb, mlb, kh, kl, wvi, lane);  // chunk 0 (drained by barrier)
    __syncthreads();  // q staged + chunk 0 landed
    // hoist q fragments (chunk-invariant)
    s16x8 fqh[2][2], fql[2][2];  // [fq][kstep]
#pragma unroll
    for (int fq = 0; fq < 2; ++fq)
#pragma unroll
        for (int ks = 0; ks < 2; ++ks) {
            int row = fq * 16 + (lane & 15);
            int kb2 = (ks * 32 + (lane >> 4) * 8) * 2;
            int by = row * 128 + (kb2 ^ ((row & 7) << 4));
            fqh[fq][ks] = *(const s16x8*)((const char*)qh + by);
            fql[fq][ks] = *(const s16x8*)((const char*)ql + by);
        }
    if (tid < 32) { cnt[tid] = 0; thrV[tid] = -FLT_MAX; }
    if (tid == 0) *sflag = 0;

    int qbase4 = (lane >> 4) * 4;  // C-frag row group

    for (int c = 0; c < NCC; ++c) {
        __syncthreads();  // A: k[c] ready (drains DMA); cnt/thr/flag consistent
        // threshold cache for this thread's 8 queries
        float thc[2][4];
#pragma unroll
        for (int fq = 0; fq < 2; ++fq)
#pragma unroll
            for (int r = 0; r < 4; ++r) thc[fq][r] = thrV[fq * 16 + qbase4 + r];

        // ---- sims: 3-pass split-bf16 MFMA; wave owns 32 m's (2 frags) ----
        f32x4 acc[2][2] = {};  // [fq][fm]
#pragma unroll
        for (int ks = 0; ks < 2; ++ks) {
            int kb2 = (ks * 32 + (lane >> 4) * 8) * 2;
#pragma unroll
            for (int fm = 0; fm < 2; ++fm) {
                int row = wvi * 32 + fm * 16 + (lane & 15);
                int by = row * 128 + (kb2 ^ ((row & 7) << 4));
                s16x8 kh8 = *(const s16x8*)((const char*)kh + by);
                s16x8 kl8 = *(const s16x8*)((const char*)kl + by);
#pragma unroll
                for (int fq = 0; fq < 2; ++fq) {
                    acc[fq][fm] = __builtin_amdgcn_mfma_f32_16x16x32_bf16(fqh[fq][ks], kh8, acc[fq][fm], 0, 0, 0);
                    acc[fq][fm] = __builtin_amdgcn_mfma_f32_16x16x32_bf16(fqh[fq][ks], kl8, acc[fq][fm], 0, 0, 0);
                    acc[fq][fm] = __builtin_amdgcn_mfma_f32_16x16x32_bf16(fql[fq][ks], kh8, acc[fq][fm], 0, 0, 0);
                }
            }
        }

        // ---- appends: unordered, threshold-gated; eager shrink flag ----
#pragma unroll
        for (int fq = 0; fq < 2; ++fq)
#pragma unroll
            for (int fm = 0; fm < 2; ++fm)
#pragma unroll
                for (int r = 0; r < 4; ++r) {
                    float v = acc[fq][fm][r];
                    if (v >= thc[fq][r]) {
                        int q = fq * 16 + qbase4 + r;
                        int pos = atomicAdd(&cnt[q], 1);
                        if (pos < CAPB) {
                            cval[q * CAPB + pos] = v;
                            cidx[q * CAPB + pos] = (ushort)(c * KCC + wvi * 32 + fm * 16 + (lane & 15));
                        }
                        if (pos == TRIG) *sflag = 1;
                    }
                }
        __syncthreads();  // B: appends done; all kh/kl reads done

        // DMA next chunk into kh/kl (async; drained by next barrier A)
        if (c + 1 < NCC) {
            size_t ro = (size_t)(c + 1) * KCC * 64;
            stage_dma(mhb + ro, mlb + ro, kh, kl, wvi, lane);
        }

        if (*sflag) {  // block-uniform: shrink ALL queries (thresholds tighten together)
#pragma unroll 1
            for (int qq = 0; qq < 8; ++qq) {
                int q = wvi * 8 + qq;
                shrink_cheap(cval, cidx, q, cnt[q], lane, &thrV[q]);
                if (lane == 0) cnt[q] = 32;
            }
            __syncthreads();  // C: shrink done
            if (tid == 0) *sflag = 0;
        }
    }

    // ---- final shrink (unconditional, exact top-32, unsorted) ----
#pragma unroll 1
    for (int qq = 0; qq < 8; ++qq) {
        int q = wvi * 8 + qq;
        shrink_cheap(cval, cidx, q, cnt[q], lane, nullptr);
    }
    __syncthreads();

    // ---- softmax weights (explicit max; slots unsorted) ----
    if (tid < 32) {
        int q = tid;
        float mx = -FLT_MAX;
#pragma unroll
        for (int j = 0; j < 32; ++j) mx = fmaxf(mx, cval[q * CAPB + j]);
        float es[32];
        float ssum = 0.f;
#pragma unroll
        for (int j = 0; j < 32; ++j) { es[j] = __expf(cval[q * CAPB + j] - mx); ssum += es[j]; }
        float inv = 1.0f / ssum;
#pragma unroll
        for (int j = 0; j < 32; ++j) cval[q * CAPB + j] = es[j] * inv;
    }
    __syncthreads();

    // ---- gather mem_v and blend into ao: 8 threads/query, 8 d each ----
    {
        int q = tid >> 3, dseg = (tid & 7) * 8;
        int h = q >> 2, si = q & 3;
        float r0x = 0, r0y = 0, r0z = 0, r0w = 0, r1x = 0, r1y = 0, r1z = 0, r1w = 0;
        const float* vb = mv + (size_t)b * NM * NHD;
        for (int j = 0; j < 32; ++j) {
            float w = cval[q * CAPB + j];
            int idx = (int)cidx[q * CAPB + j];
            const float* row = vb + (size_t)idx * NHD + dseg;
            float4 v0 = *(const float4*)(row);
            float4 v1 = *(const float4*)(row + 4);
            r0x += w * v0.x; r0y += w * v0.y; r0z += w * v0.z; r0w += w * v0.w;
            r1x += w * v1.x; r1y += w * v1.y; r1z += w * v1.z; r1w += w * v1.w;
        }
        float g = 1.0f / (1.0f + __expf(-gate[h]));
        float omg = 1.0f - g;
        float* aop = ao + ((size_t)(b * NS) + s0 + si) * ND + h * 64 + dseg;
        float rr[8] = {r0x, r0y, r0z, r0w, r1x, r1y, r1z, r1w};
#pragma unroll
        for (int k = 0; k < 8; ++k) aop[k] = aop[k] * omg + rr[k] * g;
    }
}

// ---- LayerNorm over D=512 per row ----
__global__ __launch_bounds__(256) void k_ln(const float* __restrict__ X,
                                            const float* __restrict__ gam,
                                            const float* __restrict__ bet,
                                            float* __restrict__ Y) {
    __shared__ float red[4];
    __shared__ float sm, sv;
    int r = blockIdx.x, tid = threadIdx.x;
    const float* xr = X + (size_t)r * ND;
    float x0 = xr[tid], x1 = xr[tid + 256];
    float s = x0 + x1;
    for (int off = 32; off; off >>= 1) s += __shfl_down(s, off);
    if ((tid & 63) == 0) red[tid >> 6] = s;
    __syncthreads();
    if (tid == 0) sm = (red[0] + red[1] + red[2] + red[3]) * (1.0f / 512.0f);
    __syncthreads();
    float m = sm;
    float d0 = x0 - m, d1 = x1 - m;
    float vs = d0 * d0 + d1 * d1;
    for (int off = 32; off; off >>= 1) vs += __shfl_down(vs, off);
    if ((tid & 63) == 0) red[tid >> 6] = vs;
    __syncthreads();
    if (tid == 0) sv = rsqrtf((red[0] + red[1] + red[2] + red[3]) * (1.0f / 512.0f) + 1e-5f);
    __syncthreads();
    float rstd = sv;
    Y[(size_t)r * ND + tid] = d0 * rstd * gam[tid] + bet[tid];
    Y[(size_t)r * ND + tid + 256] = d1 * rstd * gam[tid + 256] + bet[tid + 256];
}

// ---- mean pool over S ----
__global__ void k_pool(const float* __restrict__ tok, float* __restrict__ pooled) {
    int b = blockIdx.x, d = threadIdx.x;
    float s = 0.f;
    for (int sp = 0; sp < NS; ++sp) s += tok[((size_t)(b * NS) + sp) * ND + d];
    pooled[b * ND + d] = s * (1.0f / 512.0f);
}

__global__ void k_fc1(const float* __restrict__ pooled, const float* __restrict__ w,
                      const float* __restrict__ bias, float* __restrict__ o1) {
    int id = blockIdx.x * 256 + threadIdx.x;  // 4096
    int b = id >> 10, j = id & 1023;
    float acc = bias[j];
    for (int d = 0; d < ND; ++d) acc += pooled[b * ND + d] * w[(size_t)d * NMLP + j];
    o1[id] = gelu_f(acc);
}

__global__ void k_fc2(const float* __restrict__ o1, const float* __restrict__ w,
                      const float* __restrict__ bias, float* __restrict__ out) {
    int id = blockIdx.x * 256 + threadIdx.x;
    if (id >= NB * NC) return;
    int b = id / NC, c = id % NC;
    float acc = bias[c];
    for (int k = 0; k < NMLP; ++k) acc += o1[b * NMLP + k] * w[(size_t)k * NC + c];
    out[id] = acc;
}

extern "C" void kernel_launch(void* const* d_in, const int* in_sizes, int n_in,
                              void* d_out, int out_size, void* d_ws, size_t ws_size,
                              hipStream_t stream) {
    const float* x    = (const float*)d_in[0];
    const float* mask = (const float*)d_in[1];
    const float* pe   = (const float*)d_in[2];
    const float* Wqkv = (const float*)d_in[3];
    const float* bqkv = (const float*)d_in[4];
    const float* Wo   = (const float*)d_in[5];
    const float* bo   = (const float*)d_in[6];
    const float* ln1g = (const float*)d_in[7];
    const float* ln1b = (const float*)d_in[8];
    const float* W1   = (const float*)d_in[9];
    const float* b1   = (const float*)d_in[10];
    const float* W2   = (const float*)d_in[11];
    const float* b2   = (const float*)d_in[12];
    const float* ln2g = (const float*)d_in[13];
    const float* ln2b = (const float*)d_in[14];
    const float* gate = (const float*)d_in[15];
    const float* memk = (const float*)d_in[16];
    const float* memv = (const float*)d_in[17];
    const float* fc1w = (const float*)d_in[18];
    const float* fc1b = (const float*)d_in[19];
    const float* fc2w = (const float*)d_in[20];
    const float* fc2b = (const float*)d_in[21];
    float* out = (float*)d_out;

    float* ws = (float*)d_ws;
    float* m8     = ws;                       // 2048
    ushort* mkh   = (ushort*)(m8 + 2048);     // 2097152 ushort (pre-swizzled rows)
    ushort* mkl   = mkh + 2097152;            // 2097152 ushort
    float* tok    = (float*)(mkl + 2097152);  // 1048576
    float* qkv    = tok + 1048576;            // 3145728
    float* ao     = qkv + 3145728;            // 1048576
    float* ybuf   = ao + 1048576;             // 1048576
    float* ff1    = ybuf + 1048576;           // 4194304
    float* pooled = ff1 + 4194304;            // 2048
    float* o1     = pooled + 2048;            // 4096

    k_m8<<<NB, 512, 0, stream>>>(mask, m8);
    k_mksplit<<<1024, 256, 0, stream>>>(memk, mkh, mkl);
    k_tok<<<dim3(16, 16, NB), dim3(32, 8), 0, stream>>>(x, pe, m8, tok);

    for (int l = 0; l < NL; ++l) {
        k_gmm<128, 128, 0><<<dim3(12, 16), 256, 0, stream>>>(
            tok, Wqkv + (size_t)l * 512 * 1536, bqkv + l * 1536, nullptr, qkv, 2048, 1536, 512);
        k_attn<<<dim3(16, NH, NB), 256, 0, stream>>>(qkv, ao);
        if (l == 0)
            k_knn4<<<dim3(NS / 4, NB), 256, 0, stream>>>(qkv, mkh, mkl, memv, gate, ao);
        k_gmm<64, 64, 2><<<dim3(8, 32), 256, 0, stream>>>(
            ao, Wo + (size_t)l * 512 * 512, bo + l * 512, tok, ybuf, 2048, 512, 512);
        k_ln<<<2048, 256, 0, stream>>>(ybuf, ln1g + l * 512, ln1b + l * 512, tok);
        k_gmm<128, 128, 1><<<dim3(16, 16), 256, 0, stream>>>(
            tok, W1 + (size_t)l * 512 * 2048, b1 + l * 2048, nullptr, ff1, 2048, 2048, 512);
        k_gmm<64, 64, 2><<<dim3(8, 32), 256, 0, stream>>>(
            ff1, W2 + (size_t)l * 2048 * 512, b2 + l * 512, tok, ybuf, 2048, 512, 2048);
        k_ln<<<2048, 256, 0, stream>>>(ybuf, ln2g + l * 512, ln2b + l * 512, tok);
    }

    k_pool<<<NB, 512, 0, stream>>>(tok, pooled);
    k_fc1<<<16, 256, 0, stream>>>(pooled, fc1w, fc1b, o1);
    k_fc2<<<2, 256, 0, stream>>>(o1, fc2w, fc2b, out);
}